// Round 1
// 197.747 us; speedup vs baseline: 1.0138x; 1.0138x over previous
//
#include <hip/hip_runtime.h>
#include <math.h>

#define BATCH 4
#define KQ    2048
#define NPTS  4096
#define CIN   61
#define KNN   32
#define ROWS  (BATCH*KQ*KNN)   // 262144

// ---------------- ws layout (bytes) ----------------
#define OFF_IDX  0         // u16 [262144] = 524288
#define OFF_ACC  524288    // f32 [64 slots][128] = 32768 (sum 0..63 | sumsq 64..127)
#define OFF_ATTA 557056    // f32[256]
#define OFF_W1F  558080    // bf16 frag-major = 16384
#define OFF_W2F  574464    // 32768
#define OFF_W3F  607232    // 16384 (end 623616)

typedef __attribute__((ext_vector_type(8)))  short bfrag;   // 8 bf16
typedef __attribute__((ext_vector_type(16))) float cfrag;   // 32x32 acc

__device__ __forceinline__ unsigned short bf16_rne(float x) {
  unsigned u = __float_as_uint(x);
  unsigned r = u + 0x7fffu + ((u >> 16) & 1u);
  return (unsigned short)(r >> 16);
}
__device__ __forceinline__ float4 ld4u(const float* p) {  // 4B-aligned vec load
  float4 r; __builtin_memcpy(&r, p, 16); return r;
}

#define NCAND 320   // candidate cap (expected ~50-80 for this distribution)

// exact select of KNN smallest among mcount candidates (NS = ceil(mcount/64)).
// Runs on EVERY wave (redundant, identical result) so no cross-wave barrier is
// needed before feats gather: each wave writes all SEL entries itself (benign
// same-value race across waves). Only wave0 emits idx_out + rel stats.
// Early exit: if exactly KNN candidates are <= mid, that set IS the top-KNN.
template<int NS>
__device__ __forceinline__ void select_emit(
    const unsigned* __restrict__ VAL, const int* __restrict__ IDXL,
    int mcount, unsigned hib, int lane, int wid,
    const float* __restrict__ Pb, float kx, float ky, float kz,
    unsigned short* __restrict__ dst, int* __restrict__ SEL,
    float* __restrict__ accs) {
  const unsigned long long lmask = (1ull << lane) - 1ull;
  unsigned e[NS];
#pragma unroll
  for (int s = 0; s < NS; ++s) {
    int ei = s*64 + lane;
    e[s] = (ei < mcount) ? VAL[ei] : 0xffffffffu;
  }
  // tight lower bound: min over candidates (invalid lanes hold ~0 -> no effect)
  unsigned lo2 = e[0];
#pragma unroll
  for (int s = 1; s < NS; ++s) lo2 = min(lo2, e[s]);
#pragma unroll
  for (int off = 1; off < 64; off <<= 1)
    lo2 = min(lo2, (unsigned)__shfl_xor((int)lo2, off));
  unsigned hi2 = hib;   // invariant: count(<= hi2) >= KNN
  while (lo2 < hi2) {
    unsigned mid = lo2 + ((hi2 - lo2) >> 1);
    int c = 0;
#pragma unroll
    for (int s = 0; s < NS; ++s) c += (int)__popcll(__ballot(e[s] <= mid));
    if (c == KNN) { hi2 = mid; break; }   // exact set found
    if (c > KNN) hi2 = mid; else lo2 = mid + 1;
  }
  const unsigned T = hi2;
  float r0=0.f,r1=0.f,r2=0.f,r3=0.f,r4=0.f,r5=0.f;
  int base2 = 0;
#pragma unroll
  for (int s = 0; s < NS; ++s) {
    bool p = (e[s] <= T);
    unsigned long long m = __ballot(p);
    if (p) {
      int pos = base2 + (int)__popcll(m & lmask);
      if (pos < KNN) {
        int n = IDXL[s*64 + lane];
        SEL[pos] = n;
        if (wid == 0) {
          dst[pos] = (unsigned short)n;
          float dx = Pb[n*3+0]-kx, dy = Pb[n*3+1]-ky, dz = Pb[n*3+2]-kz;
          r0 += dx; r1 += dy; r2 += dz;
          r3 += dx*dx; r4 += dy*dy; r5 += dz*dz;
        }
      }
    }
    base2 += (int)__popcll(m);
  }
  if (wid == 0) {
#pragma unroll
    for (int off = 32; off > 0; off >>= 1) {
      r0 += __shfl_down(r0, off); r1 += __shfl_down(r1, off);
      r2 += __shfl_down(r2, off); r3 += __shfl_down(r3, off);
      r4 += __shfl_down(r4, off); r5 += __shfl_down(r5, off);
    }
    if (lane == 0) {
      atomicAdd(&accs[0], r0); atomicAdd(&accs[1], r1); atomicAdd(&accs[2], r2);
      atomicAdd(&accs[64], r3); atomicAdd(&accs[65], r4); atomicAdd(&accs[66], r5);
    }
  }
}

// ====== topk (blocks < 8192): bound-compact select + inline BN stats ======
// ====== prep tail (blocks >= 8192): frag-major weights + attA          ======
__global__ __launch_bounds__(256, 8) void topk_kernel(
    const float* __restrict__ keys, const float* __restrict__ points,
    const float* __restrict__ feats,
    const float* __restrict__ w1, const float* __restrict__ w2,
    const float* __restrict__ w3,
    const float* __restrict__ att_w, const float* __restrict__ att_q,
    unsigned short* __restrict__ idx_out, float* __restrict__ acc,
    short* __restrict__ w1f, short* __restrict__ w2f, short* __restrict__ w3f,
    float* __restrict__ attA) {
  if (blockIdx.x >= 8192) {   // ---- prep partition ----
    const int bb = blockIdx.x - 8192;
    if (bb == 128) {   // attA[c][h] = sum_d att_w[c, h*64+d]*att_q[h,d]
      const int t = threadIdx.x, c = t >> 2, h = t & 3;
      float s = 0.f;
      for (int d = 0; d < 64; ++d) s += att_w[c*256 + h*64 + d] * att_q[h*64 + d];
      attA[c*4 + h] = s;
      return;
    }
    // frag-major: out[((tile*KC+kc)*64+lane)*8+j] = W[k][nh]
    int t = bb * 256 + threadIdx.x;   // 32768 total
    if (t < 8192) {            // W1: NH=128, K=64, KC=4
      int j = t & 7, lane = (t >> 3) & 63, tk = t >> 9;
      int kc = tk & 3, tile = tk >> 2;
      int nh = tile*32 + (lane & 31), k = kc*16 + (lane >> 5)*8 + j;
      w1f[t] = (short)bf16_rne(w1[k*128 + nh]);
    } else if (t < 24576) {    // W2: NH=128, K=128, KC=8
      int t2 = t - 8192;
      int j = t2 & 7, lane = (t2 >> 3) & 63, tk = t2 >> 9;
      int kc = tk & 7, tile = tk >> 3;
      int nh = tile*32 + (lane & 31), k = kc*16 + (lane >> 5)*8 + j;
      w2f[t2] = (short)bf16_rne(w2[k*128 + nh]);
    } else {                   // W3: NH=64, K=128, KC=8
      int t3 = t - 24576;
      int j = t3 & 7, lane = (t3 >> 3) & 63, tk = t3 >> 9;
      int kc = tk & 7, tile = tk >> 3;
      int nh = tile*32 + (lane & 31), k = kc*16 + (lane >> 5)*8 + j;
      w3f[t3] = (short)bf16_rne(w3[k*64 + nh]);
    }
    return;
  }

  // ---- topk partition: one query per 256-thread block ----
  __shared__ unsigned VAL[NCAND];
  __shared__ int IDXL[NCAND];
  __shared__ int SEL[32];
  __shared__ unsigned HIW[4];
  __shared__ int WTOT[4];
  __shared__ float FRED[64*33];   // stride-33: conflict-free partials
  __shared__ float FQ[64*33];
  const int tid = threadIdx.x;
  const int lane = tid & 63, wid = tid >> 6;
  const int g = blockIdx.x;
  const int b = g >> 11;
  const float kx = keys[(size_t)g*3+0];
  const float ky = keys[(size_t)g*3+1];
  const float kz = keys[(size_t)g*3+2];
  const float* __restrict__ Pb = points + (size_t)b * NPTS * 3;

  // distances: 16 contiguous points/thread, 12 x float4 loads (4-pt chunks)
  unsigned u[16];
  unsigned lmin = 0xffffffffu;
#pragma unroll
  for (int c4 = 0; c4 < 4; ++c4) {
    const float* pp = Pb + (size_t)(tid*16 + c4*4) * 3;
    float4 A = ld4u(pp), B = ld4u(pp + 4), C = ld4u(pp + 8);
    float dx, dy, dz;
    dx = A.x-kx; dy = A.y-ky; dz = A.z-kz;
    u[c4*4+0] = __float_as_uint(dx*dx + dy*dy + dz*dz);
    dx = A.w-kx; dy = B.x-ky; dz = B.y-kz;
    u[c4*4+1] = __float_as_uint(dx*dx + dy*dy + dz*dz);
    dx = B.z-kx; dy = B.w-ky; dz = C.x-kz;
    u[c4*4+2] = __float_as_uint(dx*dx + dy*dy + dz*dz);
    dx = C.y-kx; dy = C.z-ky; dz = C.w-kz;
    u[c4*4+3] = __float_as_uint(dx*dx + dy*dy + dz*dz);
#pragma unroll
    for (int j = 0; j < 4; ++j) lmin = min(lmin, u[c4*4+j]);
  }
  // wave bound: a T with >=32 lane-mins <= T (upper bound for global T32).
  // range [min,max] of lane-mins; early-exit when exactly KNN pass (tightest
  // possible set-preserving bound, no need to fully converge).
  unsigned wlo = lmin, whi = lmin;
#pragma unroll
  for (int off = 1; off < 64; off <<= 1) {
    unsigned a = (unsigned)__shfl_xor((int)wlo, off);
    unsigned bmx = (unsigned)__shfl_xor((int)whi, off);
    wlo = min(wlo, a); whi = max(whi, bmx);
  }
  unsigned lo = wlo, hi = whi;
  while (lo < hi) {
    unsigned mid = lo + ((hi - lo) >> 1);
    int c = (int)__popcll(__ballot(lmin <= mid));
    if (c == KNN) { hi = mid; break; }
    if (c > KNN) hi = mid; else lo = mid + 1;
  }
  if (lane == 0) HIW[wid] = hi;
  __syncthreads();
  const unsigned hib = min(min(HIW[0],HIW[1]), min(HIW[2],HIW[3]));

  // scan-based compaction of candidates (all top-32 have d2 <= hib)
  int cnt = 0;
#pragma unroll
  for (int j = 0; j < 16; ++j) cnt += (u[j] <= hib) ? 1 : 0;
  int inc = cnt;
#pragma unroll
  for (int off = 1; off < 64; off <<= 1) {
    int t = __shfl_up(inc, off);
    if (lane >= off) inc += t;
  }
  if (lane == 63) WTOT[wid] = inc;
  __syncthreads();
  int base = inc - cnt;
  for (int w = 0; w < wid; ++w) base += WTOT[w];
  {
    int p = base;
#pragma unroll
    for (int j = 0; j < 16; ++j) {
      if (u[j] <= hib) {
        if (p < NCAND) { VAL[p] = u[j]; IDXL[p] = tid*16 + j; }
        ++p;
      }
    }
  }
  __syncthreads();
  const int mcount = min(WTOT[0]+WTOT[1]+WTOT[2]+WTOT[3], NCAND);

  // exact select on ALL waves (wave-uniform branch on mcount); each wave
  // writes the full SEL[] itself -> no barrier needed before feats gather.
  {
    unsigned short* dst = idx_out + (size_t)g * KNN;
    float* accs = &acc[(g & 63)*128];
    if (mcount <= 64)
      select_emit<1>(VAL, IDXL, mcount, hib, lane, wid, Pb, kx, ky, kz, dst, SEL, accs);
    else if (mcount <= 128)
      select_emit<2>(VAL, IDXL, mcount, hib, lane, wid, Pb, kx, ky, kz, dst, SEL, accs);
    else
      select_emit<5>(VAL, IDXL, mcount, hib, lane, wid, Pb, kx, ky, kz, dst, SEL, accs);
  }

  // feats BN stats: thread = (row = tid>>3, 8-channel chunk = tid&7)
  // (SEL written by this wave itself; no cross-wave barrier required)
  {
    const int row = tid >> 3, chunk = tid & 7;
    const int n = SEL[row];
    const float* frow = feats + ((size_t)b*NPTS + n)*CIN;
    float fs[8] = {0,0,0,0,0,0,0,0}, fq[8] = {0,0,0,0,0,0,0,0};
    if (chunk < 7) {
      float4 a = ld4u(frow + chunk*8);
      float4 c4 = ld4u(frow + chunk*8 + 4);
      fs[0]=a.x;  fq[0]=a.x*a.x;   fs[1]=a.y;  fq[1]=a.y*a.y;
      fs[2]=a.z;  fq[2]=a.z*a.z;   fs[3]=a.w;  fq[3]=a.w*a.w;
      fs[4]=c4.x; fq[4]=c4.x*c4.x; fs[5]=c4.y; fq[5]=c4.y*c4.y;
      fs[6]=c4.z; fq[6]=c4.z*c4.z; fs[7]=c4.w; fq[7]=c4.w*c4.w;
    } else {
      float v0=frow[56], v1=frow[57], v2=frow[58], v3=frow[59], v4=frow[60];
      fs[0]=v0; fq[0]=v0*v0; fs[1]=v1; fq[1]=v1*v1;
      fs[2]=v2; fq[2]=v2*v2; fs[3]=v3; fq[3]=v3*v3;
      fs[4]=v4; fq[4]=v4*v4;
    }
    // partials -> LDS: FRED[(chunk*8+i)*33 + row] (2-way max on writes)
#pragma unroll
    for (int i = 0; i < 8; ++i) {
      FRED[(chunk*8 + i)*33 + row] = fs[i];
      FQ  [(chunk*8 + i)*33 + row] = fq[i];
    }
  }
  __syncthreads();
  if (tid < 64) {   // channel tid: sum 32 row-partials (conflict-free)
    float s = 0.f, q2 = 0.f;
#pragma unroll
    for (int r = 0; r < 32; ++r) {
      s  += FRED[tid*33 + r];
      q2 += FQ[tid*33 + r];
    }
    if (tid < CIN) {
      float* a = &acc[(g & 63)*128];
      atomicAdd(&a[3 + tid], s);
      atomicAdd(&a[64 + 3 + tid], q2);
    }
  }
}

// ---------------- main-kernel LDS offsets (bytes) ----------------
#define L_W1F 0        // 16384
#define L_W2F 16384    // 32768
#define L_W3F 49152    // 16384
#define L_B1  65536    // 512
#define L_B2  66048    // 512
#define L_B3  66560    // 256
#define L_AE  66816    // f32[256]
#define L_ACT 67840    // 8 x 8704 (bf16 [32][136] / f32 [32][68]); phase0 TMP
#define L_EPX 137472   // 8 x 1024; phase0 SC scratch
#define L_TOT 145664

// per-wave GEMM: A = weight frags (frag-major LDS), B = activation frags (regs)
template<int KC, bool F32OUT>
__device__ __forceinline__ void gemm_part(const short* WF,
    const float* BIAS, short* ACTq, float* LATq,
    const bfrag* B, int tile0, int ntiles, int m, int q, int lane) {
#pragma unroll
  for (int t = 0; t < ntiles; ++t) {
    const int tile = tile0 + t;
    cfrag acc;
#pragma unroll
    for (int i = 0; i < 16; ++i) acc[i] = 0.f;
#pragma unroll
    for (int kc = 0; kc < KC; ++kc) {
      bfrag a = *(const bfrag*)(WF + ((tile*KC + kc)*64 + lane)*8);
      acc = __builtin_amdgcn_mfma_f32_32x32x16_bf16(a, B[kc], acc, 0, 0, 0);
    }
#pragma unroll
    for (int p = 0; p < 4; ++p) {
      const int nh = tile*32 + p*8 + q*4;
      float4 bv = *(const float4*)(BIAS + nh);
      if (F32OUT) {
        float4 o;
        o.x = acc[4*p+0] + bv.x; o.y = acc[4*p+1] + bv.y;
        o.z = acc[4*p+2] + bv.z; o.w = acc[4*p+3] + bv.w;
        *(float4*)(LATq + m*68 + nh) = o;
      } else {
        short4 s;
        s.x = (short)bf16_rne(fmaxf(acc[4*p+0] + bv.x, 0.f));
        s.y = (short)bf16_rne(fmaxf(acc[4*p+1] + bv.y, 0.f));
        s.z = (short)bf16_rne(fmaxf(acc[4*p+2] + bv.z, 0.f));
        s.w = (short)bf16_rne(fmaxf(acc[4*p+3] + bv.w, 0.f));
        *(short4*)(ACTq + m*136 + nh) = s;
      }
    }
  }
}

// ====== main: phase0 Ae from acc, then pipelined gather->softmax->MLP->out ===
__global__ __launch_bounds__(1024, 4) void main_kernel(
    const float* __restrict__ keys, const float* __restrict__ points,
    const float* __restrict__ feats, const unsigned short* __restrict__ idxg,
    const short* __restrict__ w1f, const short* __restrict__ w2f,
    const short* __restrict__ w3f,
    const float* __restrict__ b1, const float* __restrict__ b2,
    const float* __restrict__ b3,
    const float* __restrict__ attAg, const float* __restrict__ accg,
    const float* __restrict__ gammav, float* __restrict__ out) {
  __shared__ __align__(16) char smem[L_TOT];
  const int tid = threadIdx.x;
  const int bid = blockIdx.x;
  const int wid = tid >> 6, lane = tid & 63;
  const int pairq = wid >> 1, wv = wid & 1;
  const int m = lane & 31, q = lane >> 5;

  short* SW1 = (short*)(smem + L_W1F);
  short* SW2 = (short*)(smem + L_W2F);
  short* SW3 = (short*)(smem + L_W3F);
  float* SB1 = (float*)(smem + L_B1);
  float* SB2 = (float*)(smem + L_B2);
  float* SB3 = (float*)(smem + L_B3);
  float* SAe = (float*)(smem + L_AE);
  short* ACTq = (short*)(smem + L_ACT + pairq * 8704);
  float* LATq = (float*)(smem + L_ACT + pairq * 8704);
  float* EPX  = (float*)(smem + L_EPX) + pairq * 256;   // [32][8]

  // ---- phase 0: stage weights + compute Ae = gamma*invstd*attA ----
  {
    ((uint4*)SW1)[tid] = ((const uint4*)w1f)[tid];
    ((uint4*)SW2)[tid] = ((const uint4*)w2f)[tid];
    ((uint4*)SW2)[tid + 1024] = ((const uint4*)w2f)[tid + 1024];
    ((uint4*)SW3)[tid] = ((const uint4*)w3f)[tid];
    if (tid < 128) SB1[tid] = b1[tid];
    else if (tid < 256) SB2[tid-128] = b2[tid-128];
    else if (tid < 320) SB3[tid-256] = b3[tid-256];
    float* TMP = (float*)(smem + L_ACT);    // [8][128]
    if (tid < 512) {
      int c = tid & 63, p = tid >> 6;
      float s = 0.f, s2 = 0.f;
      for (int k = p; k < 64; k += 8) {
        s += accg[k*128 + c]; s2 += accg[k*128 + 64 + c];
      }
      TMP[p*128 + c] = s; TMP[p*128 + 64 + c] = s2;
    }
    __syncthreads();
    float* SCt = (float*)(smem + L_EPX);
    if (tid < 64) {
      float s = 0.f, s2 = 0.f;
#pragma unroll
      for (int p = 0; p < 8; ++p) { s += TMP[p*128 + tid]; s2 += TMP[p*128 + 64 + tid]; }
      const float invR = 1.f / (float)ROWS;
      float mean = s * invR;
      float var = s2 * invR - mean * mean;
      SCt[tid] = gammav[tid] * rsqrtf(var + 1e-5f);
    }
    __syncthreads();
    if (tid < 256) SAe[tid] = attAg[tid] * SCt[tid >> 2];
    __syncthreads();
  }

  // ---- gather loader (into registers) ----
  auto load_gather = [&](int grp2, float* v) {
    const int g2 = grp2 * 8 + pairq;
    const int bq2 = g2 >> 11;
    const int c0 = wv*32 + q*16;
    const int n = (int)idxg[(size_t)g2*KNN + m];
    const float* frow = feats + ((size_t)bq2*NPTS + n)*CIN;
    if (wv == 0 && q == 0) {
      const float* Pb = points + (size_t)bq2 * NPTS * 3;
      v[0] = Pb[n*3+0] - keys[(size_t)g2*3+0];
      v[1] = Pb[n*3+1] - keys[(size_t)g2*3+1];
      v[2] = Pb[n*3+2] - keys[(size_t)g2*3+2];
#pragma unroll
      for (int kk = 0; kk < 3; ++kk) {
        float4 t = ld4u(frow + kk*4);
        v[3+kk*4+0] = t.x; v[3+kk*4+1] = t.y; v[3+kk*4+2] = t.z; v[3+kk*4+3] = t.w;
      }
      v[15] = frow[12];
    } else {
      const int base = c0 - 3;
#pragma unroll
      for (int kk = 0; kk < 4; ++kk) {
        float4 t = ld4u(frow + base + kk*4);
        v[kk*4+0] = t.x; v[kk*4+1] = t.y; v[kk*4+2] = t.z; v[kk*4+3] = t.w;
      }
    }
  };

  float vcur[16];
  load_gather(bid, vcur);

  for (int grp = bid; grp < BATCH*KQ/8; grp += 256) {
    const int g = grp * 8 + pairq;
    const int c0 = wv*32 + q*16;

    {  // write ACT (bf16) + e-partials from exact f32
      float ep0 = 0.f, ep1 = 0.f, ep2 = 0.f, ep3 = 0.f;
#pragma unroll
      for (int cc = 0; cc < 16; ++cc) {
        float4 ae = *(const float4*)(SAe + (c0 + cc)*4);
        ep0 = fmaf(vcur[cc], ae.x, ep0);
        ep1 = fmaf(vcur[cc], ae.y, ep1);
        ep2 = fmaf(vcur[cc], ae.z, ep2);
        ep3 = fmaf(vcur[cc], ae.w, ep3);
      }
      ep0 += __shfl_xor(ep0, 32); ep1 += __shfl_xor(ep1, 32);
      ep2 += __shfl_xor(ep2, 32); ep3 += __shfl_xor(ep3, 32);
#pragma unroll
      for (int k = 0; k < 2; ++k) {
        bfrag pk;
#pragma unroll
        for (int t = 0; t < 8; ++t) pk[t] = (short)bf16_rne(vcur[k*8 + t]);
        *(bfrag*)(ACTq + m*136 + c0 + k*8) = pk;
      }
      if (q == 0) {
        float4 e4; e4.x = ep0; e4.y = ep1; e4.z = ep2; e4.w = ep3;
        *(float4*)(EPX + m*8 + wv*4) = e4;
      }
    }
    __syncthreads();   // B1

    // prefetch next group's gather (hidden under softmax + 3 GEMMs)
    float vnext[16];
    const int gnext = grp + 256;
    if (gnext < BATCH*KQ/8) load_gather(gnext, vnext);

    if (wv == 0) {     // softmax over 32 neighbors (n-const logit terms cancel)
      const int h0 = q*2;
      float ea = EPX[m*8 + h0]     + EPX[m*8 + 4 + h0];
      float eb = EPX[m*8 + h0 + 1] + EPX[m*8 + 5 + h0];
      float ma = ea, mb = eb;
#pragma unroll
      for (int off = 1; off < 32; off <<= 1) {
        ma = fmaxf(ma, __shfl_xor(ma, off));
        mb = fmaxf(mb, __shfl_xor(mb, off));
      }
      float xa = __expf(ea - ma), xb = __expf(eb - mb);
      float sa = xa, sb = xb;
#pragma unroll
      for (int off = 1; off < 32; off <<= 1) {
        sa += __shfl_xor(sa, off);
        sb += __shfl_xor(sb, off);
      }
      EPX[m*8 + h0]     = xa / sa;
      EPX[m*8 + h0 + 1] = xb / sb;
    }

    {  // GEMM1: 64 -> 128 relu
      bfrag B4[4];
#pragma unroll
      for (int kc = 0; kc < 4; ++kc)
        B4[kc] = *(const bfrag*)(ACTq + m*136 + kc*16 + q*8);
      __syncthreads();   // B2
      gemm_part<4, false>(SW1, SB1, ACTq, LATq, B4, wv*2, 2, m, q, lane);
    }
    __syncthreads();     // B3
    {  // GEMM2: 128 -> 128 relu
      bfrag B8[8];
#pragma unroll
      for (int kc = 0; kc < 8; ++kc)
        B8[kc] = *(const bfrag*)(ACTq + m*136 + kc*16 + q*8);
      __syncthreads();   // B4
      gemm_part<8, false>(SW2, SB2, ACTq, LATq, B8, wv*2, 2, m, q, lane);
    }
    __syncthreads();     // B5
    {  // GEMM3: 128 -> 64, f32 lat
      bfrag C8[8];
#pragma unroll
      for (int kc = 0; kc < 8; ++kc)
        C8[kc] = *(const bfrag*)(ACTq + m*136 + kc*16 + q*8);
      __syncthreads();   // B6
      gemm_part<8, true>(SW3, SB3, ACTq, LATq, C8, wv, 1, m, q, lane);
    }
    __syncthreads();     // B7

    {  // epilogue: out[o][h] = sum_n lat[n][o]*w[n][h]
      const int oi = wv*64 + lane;
      const int o = oi >> 1, hp = oi & 1;
      float a0 = 0.f, a1 = 0.f;
#pragma unroll
      for (int n2 = 0; n2 < KNN; ++n2) {
        float l = LATq[n2*68 + o];
        float2 wv2 = *(const float2*)(EPX + n2*8 + hp*2);
        a0 = fmaf(l, wv2.x, a0);
        a1 = fmaf(l, wv2.y, a1);
      }
      float2 r; r.x = a0; r.y = a1;
      *(float2*)(out + (size_t)g*256 + o*4 + hp*2) = r;
    }
    __syncthreads();     // B8: drain before next iter overwrites ACT/EPX

#pragma unroll
    for (int i = 0; i < 16; ++i) vcur[i] = vnext[i];
  }
}

extern "C" void kernel_launch(void* const* d_in, const int* in_sizes, int n_in,
                              void* d_out, int out_size, void* d_ws, size_t ws_size,
                              hipStream_t stream) {
  const float* keys   = (const float*)d_in[0];
  const float* points = (const float*)d_in[1];
  const float* feats  = (const float*)d_in[2];
  const float* nx_w1  = (const float*)d_in[3];
  const float* nx_b1  = (const float*)d_in[4];
  const float* nx_w2  = (const float*)d_in[5];
  const float* nx_b2  = (const float*)d_in[6];
  const float* nx_w3  = (const float*)d_in[7];
  const float* nx_b3  = (const float*)d_in[8];
  // sx_w*/sx_b* (9..14), att_b (16), bn_beta (19): n-constant in softmax -> dead
  const float* att_w  = (const float*)d_in[15];
  const float* att_q  = (const float*)d_in[17];
  const float* gamma  = (const float*)d_in[18];
  float* out = (float*)d_out;

  char* ws = (char*)d_ws;
  unsigned short* idxp = (unsigned short*)(ws + OFF_IDX);
  float* acc  = (float*)(ws + OFF_ACC);
  float* attA = (float*)(ws + OFF_ATTA);
  short* w1f  = (short*)(ws + OFF_W1F);
  short* w2f  = (short*)(ws + OFF_W2F);
  short* w3f  = (short*)(ws + OFF_W3F);

  hipMemsetAsync(acc, 0, 32768, stream);
  topk_kernel<<<8192 + 129, 256, 0, stream>>>(keys, points, feats,
      nx_w1, nx_w2, nx_w3, att_w, att_q, idxp, acc, w1f, w2f, w3f, attA);
  main_kernel<<<256, 1024, 0, stream>>>(keys, points, feats, idxp,
      w1f, w2f, w3f, nx_b1, nx_b2, nx_b3, attA, acc, gamma, out);
}

// Round 2
// 183.345 us; speedup vs baseline: 1.0934x; 1.0785x over previous
//
#include <hip/hip_runtime.h>
#include <math.h>

#define BATCH 4
#define KQ    2048
#define NPTS  4096
#define CIN   61
#define KNN   32
#define ROWS  (BATCH*KQ*KNN)   // 262144

// ---------------- ws layout (bytes) ----------------
#define OFF_IDX  0         // u16 [262144] = 524288
#define OFF_ACC  524288    // f32 [64 slots][128] = 32768 (sum 0..63 | sumsq 64..127)
#define OFF_ATTA 557056    // f32[256]
#define OFF_W1F  558080    // bf16 frag-major = 16384
#define OFF_W2F  574464    // 32768
#define OFF_W3F  607232    // 16384 (end 623616)

typedef __attribute__((ext_vector_type(8)))  short bfrag;   // 8 bf16
typedef __attribute__((ext_vector_type(16))) float cfrag;   // 32x32 acc

__device__ __forceinline__ unsigned short bf16_rne(float x) {
  unsigned u = __float_as_uint(x);
  unsigned r = u + 0x7fffu + ((u >> 16) & 1u);
  return (unsigned short)(r >> 16);
}
__device__ __forceinline__ float4 ld4u(const float* p) {  // 4B-aligned vec load
  float4 r; __builtin_memcpy(&r, p, 16); return r;
}

#define NCAND 320   // candidate cap per query (expected ~50-80)

// exact select of KNN smallest among mcount candidates (NS = ceil(mcount/64)).
// Called by ONE wave per query. Early exit: count==KNN -> that set IS top-KNN.
template<int NS>
__device__ __forceinline__ void select_emit(
    const unsigned* __restrict__ VAL, const int* __restrict__ IDXL,
    int mcount, unsigned hib, unsigned lob, int lane,
    const float* __restrict__ Pb, float kx, float ky, float kz,
    unsigned short* __restrict__ dst, int* __restrict__ SEL,
    float* __restrict__ accs) {
  const unsigned long long lmask = (1ull << lane) - 1ull;
  unsigned e[NS];
#pragma unroll
  for (int s = 0; s < NS; ++s) {
    int ei = s*64 + lane;
    e[s] = (ei < mcount) ? VAL[ei] : 0xffffffffu;
  }
  unsigned lo2 = lob, hi2 = hib;   // invariant: count(<= hi2) >= KNN
  while (lo2 < hi2) {
    unsigned mid = lo2 + ((hi2 - lo2) >> 1);
    int c = 0;
#pragma unroll
    for (int s = 0; s < NS; ++s) c += (int)__popcll(__ballot(e[s] <= mid));
    if (c == KNN) { hi2 = mid; break; }   // exact set found
    if (c > KNN) hi2 = mid; else lo2 = mid + 1;
  }
  const unsigned T = hi2;
  float r0=0.f,r1=0.f,r2=0.f,r3=0.f,r4=0.f,r5=0.f;
  int base2 = 0;
#pragma unroll
  for (int s = 0; s < NS; ++s) {
    bool p = (e[s] <= T);
    unsigned long long m = __ballot(p);
    if (p) {
      int pos = base2 + (int)__popcll(m & lmask);
      if (pos < KNN) {
        int n = IDXL[s*64 + lane];
        SEL[pos] = n;
        dst[pos] = (unsigned short)n;
        float dx = Pb[n*3+0]-kx, dy = Pb[n*3+1]-ky, dz = Pb[n*3+2]-kz;
        r0 += dx; r1 += dy; r2 += dz;
        r3 += dx*dx; r4 += dy*dy; r5 += dz*dz;
      }
    }
    base2 += (int)__popcll(m);
  }
#pragma unroll
  for (int off = 32; off > 0; off >>= 1) {
    r0 += __shfl_down(r0, off); r1 += __shfl_down(r1, off);
    r2 += __shfl_down(r2, off); r3 += __shfl_down(r3, off);
    r4 += __shfl_down(r4, off); r5 += __shfl_down(r5, off);
  }
  if (lane == 0) {
    atomicAdd(&accs[0], r0); atomicAdd(&accs[1], r1); atomicAdd(&accs[2], r2);
    atomicAdd(&accs[64], r3); atomicAdd(&accs[65], r4); atomicAdd(&accs[66], r5);
  }
}

__device__ __forceinline__ void dispatch_select(
    const unsigned* VAL, const int* IDXL, int mcount, unsigned hib, unsigned lob,
    int lane, const float* Pb, float kx, float ky, float kz,
    unsigned short* dst, int* SEL, float* accs) {
  if (mcount <= 64)
    select_emit<1>(VAL, IDXL, mcount, hib, lob, lane, Pb, kx, ky, kz, dst, SEL, accs);
  else if (mcount <= 128)
    select_emit<2>(VAL, IDXL, mcount, hib, lob, lane, Pb, kx, ky, kz, dst, SEL, accs);
  else
    select_emit<5>(VAL, IDXL, mcount, hib, lob, lane, Pb, kx, ky, kz, dst, SEL, accs);
}

// ====== topk (blocks < 4096): TWO queries per block ======
// ====== prep tail (blocks >= 4096): frag-major weights + attA ======
__global__ __launch_bounds__(256, 6) void topk_kernel(
    const float* __restrict__ keys, const float* __restrict__ points,
    const float* __restrict__ feats,
    const float* __restrict__ w1, const float* __restrict__ w2,
    const float* __restrict__ w3,
    const float* __restrict__ att_w, const float* __restrict__ att_q,
    unsigned short* __restrict__ idx_out, float* __restrict__ acc,
    short* __restrict__ w1f, short* __restrict__ w2f, short* __restrict__ w3f,
    float* __restrict__ attA) {
  if (blockIdx.x >= 4096) {   // ---- prep partition ----
    const int bb = blockIdx.x - 4096;
    if (bb == 128) {   // attA[c][h] = sum_d att_w[c, h*64+d]*att_q[h,d]
      const int t = threadIdx.x, c = t >> 2, h = t & 3;
      float s = 0.f;
      for (int d = 0; d < 64; ++d) s += att_w[c*256 + h*64 + d] * att_q[h*64 + d];
      attA[c*4 + h] = s;
      return;
    }
    // frag-major: out[((tile*KC+kc)*64+lane)*8+j] = W[k][nh]
    int t = bb * 256 + threadIdx.x;   // 32768 total
    if (t < 8192) {            // W1: NH=128, K=64, KC=4
      int j = t & 7, lane = (t >> 3) & 63, tk = t >> 9;
      int kc = tk & 3, tile = tk >> 2;
      int nh = tile*32 + (lane & 31), k = kc*16 + (lane >> 5)*8 + j;
      w1f[t] = (short)bf16_rne(w1[k*128 + nh]);
    } else if (t < 24576) {    // W2: NH=128, K=128, KC=8
      int t2 = t - 8192;
      int j = t2 & 7, lane = (t2 >> 3) & 63, tk = t2 >> 9;
      int kc = tk & 7, tile = tk >> 3;
      int nh = tile*32 + (lane & 31), k = kc*16 + (lane >> 5)*8 + j;
      w2f[t2] = (short)bf16_rne(w2[k*128 + nh]);
    } else {                   // W3: NH=64, K=128, KC=8
      int t3 = t - 24576;
      int j = t3 & 7, lane = (t3 >> 3) & 63, tk = t3 >> 9;
      int kc = tk & 7, tile = tk >> 3;
      int nh = tile*32 + (lane & 31), k = kc*16 + (lane >> 5)*8 + j;
      w3f[t3] = (short)bf16_rne(w3[k*64 + nh]);
    }
    return;
  }

  // ---- topk partition: queries g0=2*bid, g1=g0+1 (same batch always) ----
  __shared__ unsigned VAL[2][NCAND];
  __shared__ int IDXL[2][NCAND];
  __shared__ int SEL[2][KNN];
  __shared__ unsigned HIW[2][4], LOW[2][4];
  __shared__ int WTOT[2][4];
  __shared__ float FRED[64*33];   // merged A+B partials, stride-33
  __shared__ float FQ[64*33];
  const int tid = threadIdx.x;
  const int lane = tid & 63, wid = tid >> 6;
  const int g0 = blockIdx.x * 2, g1 = g0 + 1;
  const int b = g0 >> 11;
  const float kxA = keys[(size_t)g0*3+0], kyA = keys[(size_t)g0*3+1], kzA = keys[(size_t)g0*3+2];
  const float kxB = keys[(size_t)g1*3+0], kyB = keys[(size_t)g1*3+1], kzB = keys[(size_t)g1*3+2];
  const float* __restrict__ Pb = points + (size_t)b * NPTS * 3;

  // distances for BOTH queries: 16 contiguous points/thread, shared loads
  unsigned uA[16], uB[16];
  unsigned lminA = 0xffffffffu, lminB = 0xffffffffu;
#pragma unroll
  for (int c4 = 0; c4 < 4; ++c4) {
    const float* pp = Pb + (size_t)(tid*16 + c4*4) * 3;
    float4 A = ld4u(pp), B4 = ld4u(pp + 4), C4 = ld4u(pp + 8);
    float x, y, z, dx, dy, dz;
#define DPT(slot, PX, PY, PZ)                                        \
    x = PX; y = PY; z = PZ;                                          \
    dx = x-kxA; dy = y-kyA; dz = z-kzA;                              \
    uA[slot] = __float_as_uint(dx*dx + dy*dy + dz*dz);               \
    lminA = min(lminA, uA[slot]);                                    \
    dx = x-kxB; dy = y-kyB; dz = z-kzB;                              \
    uB[slot] = __float_as_uint(dx*dx + dy*dy + dz*dz);               \
    lminB = min(lminB, uB[slot]);
    DPT(c4*4+0, A.x,  A.y,  A.z)
    DPT(c4*4+1, A.w,  B4.x, B4.y)
    DPT(c4*4+2, B4.z, B4.w, C4.x)
    DPT(c4*4+3, C4.y, C4.z, C4.w)
#undef DPT
  }
  // per-wave [min,max] of lane-mins for both queries
  unsigned wloA = lminA, whiA = lminA, wloB = lminB, whiB = lminB;
#pragma unroll
  for (int off = 1; off < 64; off <<= 1) {
    unsigned a0 = (unsigned)__shfl_xor((int)wloA, off);
    unsigned a1 = (unsigned)__shfl_xor((int)whiA, off);
    unsigned b0 = (unsigned)__shfl_xor((int)wloB, off);
    unsigned b1 = (unsigned)__shfl_xor((int)whiB, off);
    wloA = min(wloA, a0); whiA = max(whiA, a1);
    wloB = min(wloB, b0); whiB = max(whiB, b1);
  }
  // wave bound: value with >=KNN lane-mins <= it (valid upper bound on T32).
  // early-exit when exactly KNN pass.
  unsigned hiA, hiB;
  {
    unsigned lo = wloA, hi = whiA;
    while (lo < hi) {
      unsigned mid = lo + ((hi - lo) >> 1);
      int c = (int)__popcll(__ballot(lminA <= mid));
      if (c == KNN) { hi = mid; break; }
      if (c > KNN) hi = mid; else lo = mid + 1;
    }
    hiA = hi;
    lo = wloB; hi = whiB;
    while (lo < hi) {
      unsigned mid = lo + ((hi - lo) >> 1);
      int c = (int)__popcll(__ballot(lminB <= mid));
      if (c == KNN) { hi = mid; break; }
      if (c > KNN) hi = mid; else lo = mid + 1;
    }
    hiB = hi;
  }
  if (lane == 0) {
    HIW[0][wid] = hiA; HIW[1][wid] = hiB;
    LOW[0][wid] = wloA; LOW[1][wid] = wloB;
  }
  __syncthreads();   // S1
  const unsigned hibA = min(min(HIW[0][0],HIW[0][1]), min(HIW[0][2],HIW[0][3]));
  const unsigned hibB = min(min(HIW[1][0],HIW[1][1]), min(HIW[1][2],HIW[1][3]));
  const unsigned lobA = min(min(LOW[0][0],LOW[0][1]), min(LOW[0][2],LOW[0][3]));
  const unsigned lobB = min(min(LOW[1][0],LOW[1][1]), min(LOW[1][2],LOW[1][3]));

  // counts + interleaved exclusive scans
  int cntA = 0, cntB = 0;
#pragma unroll
  for (int j = 0; j < 16; ++j) {
    cntA += (uA[j] <= hibA) ? 1 : 0;
    cntB += (uB[j] <= hibB) ? 1 : 0;
  }
  int incA = cntA, incB = cntB;
#pragma unroll
  for (int off = 1; off < 64; off <<= 1) {
    int tA = __shfl_up(incA, off);
    int tB = __shfl_up(incB, off);
    if (lane >= off) { incA += tA; incB += tB; }
  }
  if (lane == 63) { WTOT[0][wid] = incA; WTOT[1][wid] = incB; }
  __syncthreads();   // S2
  int baseA = incA - cntA, baseB = incB - cntB;
  for (int w = 0; w < wid; ++w) { baseA += WTOT[0][w]; baseB += WTOT[1][w]; }
  {
    int pA = baseA, pB = baseB;
#pragma unroll
    for (int j = 0; j < 16; ++j) {
      if (uA[j] <= hibA) {
        if (pA < NCAND) { VAL[0][pA] = uA[j]; IDXL[0][pA] = tid*16 + j; }
        ++pA;
      }
      if (uB[j] <= hibB) {
        if (pB < NCAND) { VAL[1][pB] = uB[j]; IDXL[1][pB] = tid*16 + j; }
        ++pB;
      }
    }
  }
  __syncthreads();   // S3
  const int mcountA = min(WTOT[0][0]+WTOT[0][1]+WTOT[0][2]+WTOT[0][3], NCAND);
  const int mcountB = min(WTOT[1][0]+WTOT[1][1]+WTOT[1][2]+WTOT[1][3], NCAND);

  // exact select: wave0 -> query A, wave2 -> query B (others idle to barrier)
  float* accs = &acc[(blockIdx.x & 63)*128];
  if (wid == 0) {
    dispatch_select(VAL[0], IDXL[0], mcountA, hibA, lobA, lane, Pb,
                    kxA, kyA, kzA, idx_out + (size_t)g0*KNN, SEL[0], accs);
  } else if (wid == 2) {
    dispatch_select(VAL[1], IDXL[1], mcountB, hibB, lobB, lane, Pb,
                    kxB, kyB, kzB, idx_out + (size_t)g1*KNN, SEL[1], accs);
  }
  __syncthreads();   // S4: SEL[0], SEL[1] ready

  // feats BN stats, merged over both queries: thread = (row=tid>>3, chunk=tid&7)
  {
    const int row = tid >> 3, chunk = tid & 7;
    const int nA = SEL[0][row], nB = SEL[1][row];
    const float* frA = feats + ((size_t)b*NPTS + nA)*CIN;
    const float* frB = feats + ((size_t)b*NPTS + nB)*CIN;
    float fs[8] = {0,0,0,0,0,0,0,0}, fq[8] = {0,0,0,0,0,0,0,0};
    if (chunk < 7) {
      float4 a0 = ld4u(frA + chunk*8), a1 = ld4u(frA + chunk*8 + 4);
      float4 b0 = ld4u(frB + chunk*8), b1 = ld4u(frB + chunk*8 + 4);
      fs[0]=a0.x+b0.x; fq[0]=a0.x*a0.x+b0.x*b0.x;
      fs[1]=a0.y+b0.y; fq[1]=a0.y*a0.y+b0.y*b0.y;
      fs[2]=a0.z+b0.z; fq[2]=a0.z*a0.z+b0.z*b0.z;
      fs[3]=a0.w+b0.w; fq[3]=a0.w*a0.w+b0.w*b0.w;
      fs[4]=a1.x+b1.x; fq[4]=a1.x*a1.x+b1.x*b1.x;
      fs[5]=a1.y+b1.y; fq[5]=a1.y*a1.y+b1.y*b1.y;
      fs[6]=a1.z+b1.z; fq[6]=a1.z*a1.z+b1.z*b1.z;
      fs[7]=a1.w+b1.w; fq[7]=a1.w*a1.w+b1.w*b1.w;
    } else {
#pragma unroll
      for (int i = 0; i < 5; ++i) {
        float va = frA[56+i], vb = frB[56+i];
        fs[i] = va + vb; fq[i] = va*va + vb*vb;
      }
    }
#pragma unroll
    for (int i = 0; i < 8; ++i) {
      FRED[(chunk*8 + i)*33 + row] = fs[i];
      FQ  [(chunk*8 + i)*33 + row] = fq[i];
    }
  }
  __syncthreads();   // S5
  if (tid < 64) {   // channel tid: sum 32 row-partials (conflict-free)
    float s = 0.f, q2 = 0.f;
#pragma unroll
    for (int r = 0; r < 32; ++r) {
      s  += FRED[tid*33 + r];
      q2 += FQ[tid*33 + r];
    }
    if (tid < CIN) {
      atomicAdd(&accs[3 + tid], s);
      atomicAdd(&accs[64 + 3 + tid], q2);
    }
  }
}

// ---------------- main-kernel LDS offsets (bytes) ----------------
#define L_W1F 0        // 16384
#define L_W2F 16384    // 32768
#define L_W3F 49152    // 16384
#define L_B1  65536    // 512
#define L_B2  66048    // 512
#define L_B3  66560    // 256
#define L_AE  66816    // f32[256]
#define L_ACT 67840    // 8 x 8704 (bf16 [32][136] / f32 [32][68]); phase0 TMP
#define L_EPX 137472   // 8 x 1024; phase0 SC scratch
#define L_TOT 145664

// per-wave GEMM: A = weight frags (frag-major LDS), B = activation frags (regs)
template<int KC, bool F32OUT>
__device__ __forceinline__ void gemm_part(const short* WF,
    const float* BIAS, short* ACTq, float* LATq,
    const bfrag* B, int tile0, int ntiles, int m, int q, int lane) {
#pragma unroll
  for (int t = 0; t < ntiles; ++t) {
    const int tile = tile0 + t;
    cfrag acc;
#pragma unroll
    for (int i = 0; i < 16; ++i) acc[i] = 0.f;
#pragma unroll
    for (int kc = 0; kc < KC; ++kc) {
      bfrag a = *(const bfrag*)(WF + ((tile*KC + kc)*64 + lane)*8);
      acc = __builtin_amdgcn_mfma_f32_32x32x16_bf16(a, B[kc], acc, 0, 0, 0);
    }
#pragma unroll
    for (int p = 0; p < 4; ++p) {
      const int nh = tile*32 + p*8 + q*4;
      float4 bv = *(const float4*)(BIAS + nh);
      if (F32OUT) {
        float4 o;
        o.x = acc[4*p+0] + bv.x; o.y = acc[4*p+1] + bv.y;
        o.z = acc[4*p+2] + bv.z; o.w = acc[4*p+3] + bv.w;
        *(float4*)(LATq + m*68 + nh) = o;
      } else {
        short4 s;
        s.x = (short)bf16_rne(fmaxf(acc[4*p+0] + bv.x, 0.f));
        s.y = (short)bf16_rne(fmaxf(acc[4*p+1] + bv.y, 0.f));
        s.z = (short)bf16_rne(fmaxf(acc[4*p+2] + bv.z, 0.f));
        s.w = (short)bf16_rne(fmaxf(acc[4*p+3] + bv.w, 0.f));
        *(short4*)(ACTq + m*136 + nh) = s;
      }
    }
  }
}

// ====== main: phase0 Ae from acc, then pipelined gather->softmax->MLP->out ===
__global__ __launch_bounds__(1024, 4) void main_kernel(
    const float* __restrict__ keys, const float* __restrict__ points,
    const float* __restrict__ feats, const unsigned short* __restrict__ idxg,
    const short* __restrict__ w1f, const short* __restrict__ w2f,
    const short* __restrict__ w3f,
    const float* __restrict__ b1, const float* __restrict__ b2,
    const float* __restrict__ b3,
    const float* __restrict__ attAg, const float* __restrict__ accg,
    const float* __restrict__ gammav, float* __restrict__ out) {
  __shared__ __align__(16) char smem[L_TOT];
  const int tid = threadIdx.x;
  const int bid = blockIdx.x;
  const int wid = tid >> 6, lane = tid & 63;
  const int pairq = wid >> 1, wv = wid & 1;
  const int m = lane & 31, q = lane >> 5;

  short* SW1 = (short*)(smem + L_W1F);
  short* SW2 = (short*)(smem + L_W2F);
  short* SW3 = (short*)(smem + L_W3F);
  float* SB1 = (float*)(smem + L_B1);
  float* SB2 = (float*)(smem + L_B2);
  float* SB3 = (float*)(smem + L_B3);
  float* SAe = (float*)(smem + L_AE);
  short* ACTq = (short*)(smem + L_ACT + pairq * 8704);
  float* LATq = (float*)(smem + L_ACT + pairq * 8704);
  float* EPX  = (float*)(smem + L_EPX) + pairq * 256;   // [32][8]

  // ---- phase 0: stage weights + compute Ae = gamma*invstd*attA ----
  {
    ((uint4*)SW1)[tid] = ((const uint4*)w1f)[tid];
    ((uint4*)SW2)[tid] = ((const uint4*)w2f)[tid];
    ((uint4*)SW2)[tid + 1024] = ((const uint4*)w2f)[tid + 1024];
    ((uint4*)SW3)[tid] = ((const uint4*)w3f)[tid];
    if (tid < 128) SB1[tid] = b1[tid];
    else if (tid < 256) SB2[tid-128] = b2[tid-128];
    else if (tid < 320) SB3[tid-256] = b3[tid-256];
    float* TMP = (float*)(smem + L_ACT);    // [8][128]
    if (tid < 512) {
      int c = tid & 63, p = tid >> 6;
      float s = 0.f, s2 = 0.f;
      for (int k = p; k < 64; k += 8) {
        s += accg[k*128 + c]; s2 += accg[k*128 + 64 + c];
      }
      TMP[p*128 + c] = s; TMP[p*128 + 64 + c] = s2;
    }
    __syncthreads();
    float* SCt = (float*)(smem + L_EPX);
    if (tid < 64) {
      float s = 0.f, s2 = 0.f;
#pragma unroll
      for (int p = 0; p < 8; ++p) { s += TMP[p*128 + tid]; s2 += TMP[p*128 + 64 + tid]; }
      const float invR = 1.f / (float)ROWS;
      float mean = s * invR;
      float var = s2 * invR - mean * mean;
      SCt[tid] = gammav[tid] * rsqrtf(var + 1e-5f);
    }
    __syncthreads();
    if (tid < 256) SAe[tid] = attAg[tid] * SCt[tid >> 2];
    __syncthreads();
  }

  // ---- gather loader (into registers) ----
  auto load_gather = [&](int grp2, float* v) {
    const int g2 = grp2 * 8 + pairq;
    const int bq2 = g2 >> 11;
    const int c0 = wv*32 + q*16;
    const int n = (int)idxg[(size_t)g2*KNN + m];
    const float* frow = feats + ((size_t)bq2*NPTS + n)*CIN;
    if (wv == 0 && q == 0) {
      const float* Pb = points + (size_t)bq2 * NPTS * 3;
      v[0] = Pb[n*3+0] - keys[(size_t)g2*3+0];
      v[1] = Pb[n*3+1] - keys[(size_t)g2*3+1];
      v[2] = Pb[n*3+2] - keys[(size_t)g2*3+2];
#pragma unroll
      for (int kk = 0; kk < 3; ++kk) {
        float4 t = ld4u(frow + kk*4);
        v[3+kk*4+0] = t.x; v[3+kk*4+1] = t.y; v[3+kk*4+2] = t.z; v[3+kk*4+3] = t.w;
      }
      v[15] = frow[12];
    } else {
      const int base = c0 - 3;
#pragma unroll
      for (int kk = 0; kk < 4; ++kk) {
        float4 t = ld4u(frow + base + kk*4);
        v[kk*4+0] = t.x; v[kk*4+1] = t.y; v[kk*4+2] = t.z; v[kk*4+3] = t.w;
      }
    }
  };

  float vcur[16];
  load_gather(bid, vcur);

  for (int grp = bid; grp < BATCH*KQ/8; grp += 256) {
    const int g = grp * 8 + pairq;
    const int c0 = wv*32 + q*16;

    {  // write ACT (bf16) + e-partials from exact f32
      float ep0 = 0.f, ep1 = 0.f, ep2 = 0.f, ep3 = 0.f;
#pragma unroll
      for (int cc = 0; cc < 16; ++cc) {
        float4 ae = *(const float4*)(SAe + (c0 + cc)*4);
        ep0 = fmaf(vcur[cc], ae.x, ep0);
        ep1 = fmaf(vcur[cc], ae.y, ep1);
        ep2 = fmaf(vcur[cc], ae.z, ep2);
        ep3 = fmaf(vcur[cc], ae.w, ep3);
      }
      ep0 += __shfl_xor(ep0, 32); ep1 += __shfl_xor(ep1, 32);
      ep2 += __shfl_xor(ep2, 32); ep3 += __shfl_xor(ep3, 32);
#pragma unroll
      for (int k = 0; k < 2; ++k) {
        bfrag pk;
#pragma unroll
        for (int t = 0; t < 8; ++t) pk[t] = (short)bf16_rne(vcur[k*8 + t]);
        *(bfrag*)(ACTq + m*136 + c0 + k*8) = pk;
      }
      if (q == 0) {
        float4 e4; e4.x = ep0; e4.y = ep1; e4.z = ep2; e4.w = ep3;
        *(float4*)(EPX + m*8 + wv*4) = e4;
      }
    }
    __syncthreads();   // B1

    // prefetch next group's gather (hidden under softmax + 3 GEMMs)
    float vnext[16];
    const int gnext = grp + 256;
    if (gnext < BATCH*KQ/8) load_gather(gnext, vnext);

    if (wv == 0) {     // softmax over 32 neighbors (n-const logit terms cancel)
      const int h0 = q*2;
      float ea = EPX[m*8 + h0]     + EPX[m*8 + 4 + h0];
      float eb = EPX[m*8 + h0 + 1] + EPX[m*8 + 5 + h0];
      float ma = ea, mb = eb;
#pragma unroll
      for (int off = 1; off < 32; off <<= 1) {
        ma = fmaxf(ma, __shfl_xor(ma, off));
        mb = fmaxf(mb, __shfl_xor(mb, off));
      }
      float xa = __expf(ea - ma), xb = __expf(eb - mb);
      float sa = xa, sb = xb;
#pragma unroll
      for (int off = 1; off < 32; off <<= 1) {
        sa += __shfl_xor(sa, off);
        sb += __shfl_xor(sb, off);
      }
      EPX[m*8 + h0]     = xa / sa;
      EPX[m*8 + h0 + 1] = xb / sb;
    }

    {  // GEMM1: 64 -> 128 relu
      bfrag B4[4];
#pragma unroll
      for (int kc = 0; kc < 4; ++kc)
        B4[kc] = *(const bfrag*)(ACTq + m*136 + kc*16 + q*8);
      __syncthreads();   // B2
      gemm_part<4, false>(SW1, SB1, ACTq, LATq, B4, wv*2, 2, m, q, lane);
    }
    __syncthreads();     // B3
    {  // GEMM2: 128 -> 128 relu
      bfrag B8[8];
#pragma unroll
      for (int kc = 0; kc < 8; ++kc)
        B8[kc] = *(const bfrag*)(ACTq + m*136 + kc*16 + q*8);
      __syncthreads();   // B4
      gemm_part<8, false>(SW2, SB2, ACTq, LATq, B8, wv*2, 2, m, q, lane);
    }
    __syncthreads();     // B5
    {  // GEMM3: 128 -> 64, f32 lat
      bfrag C8[8];
#pragma unroll
      for (int kc = 0; kc < 8; ++kc)
        C8[kc] = *(const bfrag*)(ACTq + m*136 + kc*16 + q*8);
      __syncthreads();   // B6
      gemm_part<8, true>(SW3, SB3, ACTq, LATq, C8, wv, 1, m, q, lane);
    }
    __syncthreads();     // B7

    {  // epilogue: out[o][h] = sum_n lat[n][o]*w[n][h]
      const int oi = wv*64 + lane;
      const int o = oi >> 1, hp = oi & 1;
      float a0 = 0.f, a1 = 0.f;
#pragma unroll
      for (int n2 = 0; n2 < KNN; ++n2) {
        float l = LATq[n2*68 + o];
        float2 wv2 = *(const float2*)(EPX + n2*8 + hp*2);
        a0 = fmaf(l, wv2.x, a0);
        a1 = fmaf(l, wv2.y, a1);
      }
      float2 r; r.x = a0; r.y = a1;
      *(float2*)(out + (size_t)g*256 + o*4 + hp*2) = r;
    }
    __syncthreads();     // B8: drain before next iter overwrites ACT/EPX

#pragma unroll
    for (int i = 0; i < 16; ++i) vcur[i] = vnext[i];
  }
}

extern "C" void kernel_launch(void* const* d_in, const int* in_sizes, int n_in,
                              void* d_out, int out_size, void* d_ws, size_t ws_size,
                              hipStream_t stream) {
  const float* keys   = (const float*)d_in[0];
  const float* points = (const float*)d_in[1];
  const float* feats  = (const float*)d_in[2];
  const float* nx_w1  = (const float*)d_in[3];
  const float* nx_b1  = (const float*)d_in[4];
  const float* nx_w2  = (const float*)d_in[5];
  const float* nx_b2  = (const float*)d_in[6];
  const float* nx_w3  = (const float*)d_in[7];
  const float* nx_b3  = (const float*)d_in[8];
  // sx_w*/sx_b* (9..14), att_b (16), bn_beta (19): n-constant in softmax -> dead
  const float* att_w  = (const float*)d_in[15];
  const float* att_q  = (const float*)d_in[17];
  const float* gamma  = (const float*)d_in[18];
  float* out = (float*)d_out;

  char* ws = (char*)d_ws;
  unsigned short* idxp = (unsigned short*)(ws + OFF_IDX);
  float* acc  = (float*)(ws + OFF_ACC);
  float* attA = (float*)(ws + OFF_ATTA);
  short* w1f  = (short*)(ws + OFF_W1F);
  short* w2f  = (short*)(ws + OFF_W2F);
  short* w3f  = (short*)(ws + OFF_W3F);

  hipMemsetAsync(acc, 0, 32768, stream);
  topk_kernel<<<4096 + 129, 256, 0, stream>>>(keys, points, feats,
      nx_w1, nx_w2, nx_w3, att_w, att_q, idxp, acc, w1f, w2f, w3f, attA);
  main_kernel<<<256, 1024, 0, stream>>>(keys, points, feats, idxp,
      w1f, w2f, w3f, nx_b1, nx_b2, nx_b3, attA, acc, gamma, out);
}

// Round 3
// 167.106 us; speedup vs baseline: 1.1996x; 1.0972x over previous
//
#include <hip/hip_runtime.h>
#include <math.h>

#define BATCH 4
#define KQ    2048
#define NPTS  4096
#define CIN   61
#define KNN   32
#define ROWS  (BATCH*KQ*KNN)   // 262144

// ---------------- ws layout (bytes) ----------------
#define OFF_IDX  0         // u16 [262144] = 524288
#define OFF_ACC  524288    // f32 [64 slots][128] = 32768 (sum 0..63 | sumsq 64..127)
#define OFF_ATTA 557056    // f32[256]
#define OFF_W1F  558080    // bf16 frag-major = 16384
#define OFF_W2F  574464    // 32768
#define OFF_W3F  607232    // 16384 (end 623616)

typedef __attribute__((ext_vector_type(8)))  short bfrag;     // 8 bf16
typedef __attribute__((ext_vector_type(4)))  unsigned ufrag;  // 8 bf16 as 4 u32
typedef __attribute__((ext_vector_type(16))) float cfrag;     // 32x32 acc

__device__ __forceinline__ unsigned short bf16_rne(float x) {
  unsigned u = __float_as_uint(x);
  unsigned r = u + 0x7fffu + ((u >> 16) & 1u);
  return (unsigned short)(r >> 16);
}
__device__ __forceinline__ float4 ld4u(const float* p) {  // 4B-aligned vec load
  float4 r; __builtin_memcpy(&r, p, 16); return r;
}
__device__ __forceinline__ unsigned cvtpk(float lo, float hi) {
  unsigned r;
  asm("v_cvt_pk_bf16_f32 %0, %1, %2" : "=v"(r) : "v"(lo), "v"(hi));
  return r;
}
__device__ __forceinline__ float up_lo(unsigned pk) { return __uint_as_float(pk << 16); }
__device__ __forceinline__ float up_hi(unsigned pk) { return __uint_as_float(pk & 0xffff0000u); }

__device__ __forceinline__ cfrag zero16() {
  cfrag z;
#pragma unroll
  for (int i = 0; i < 16; ++i) z[i] = 0.f;
  return z;
}
__device__ __forceinline__ cfrag mfma_bu(bfrag a, ufrag b, cfrag c) {
  return __builtin_amdgcn_mfma_f32_32x32x16_bf16(a, __builtin_bit_cast(bfrag, b), c, 0, 0, 0);
}
__device__ __forceinline__ cfrag mfma_ub(ufrag a, bfrag b, cfrag c) {
  return __builtin_amdgcn_mfma_f32_32x32x16_bf16(__builtin_bit_cast(bfrag, a), b, c, 0, 0, 0);
}
__device__ __forceinline__ cfrag mfma_uu(ufrag a, ufrag b, cfrag c) {
  return __builtin_amdgcn_mfma_f32_32x32x16_bf16(__builtin_bit_cast(bfrag, a), __builtin_bit_cast(bfrag, b), c, 0, 0, 0);
}

#define NCAND 320   // candidate cap per query (expected ~50-80)

// exact select of KNN smallest among mcount candidates (NS = ceil(mcount/64)).
template<int NS>
__device__ __forceinline__ void select_emit(
    const unsigned* __restrict__ VAL, const int* __restrict__ IDXL,
    int mcount, unsigned hib, unsigned lob, int lane,
    const float* __restrict__ Pb, float kx, float ky, float kz,
    unsigned short* __restrict__ dst, int* __restrict__ SEL,
    float* __restrict__ accs) {
  const unsigned long long lmask = (1ull << lane) - 1ull;
  unsigned e[NS];
#pragma unroll
  for (int s = 0; s < NS; ++s) {
    int ei = s*64 + lane;
    e[s] = (ei < mcount) ? VAL[ei] : 0xffffffffu;
  }
  unsigned lo2 = lob, hi2 = hib;   // invariant: count(<= hi2) >= KNN
  while (lo2 < hi2) {
    unsigned mid = lo2 + ((hi2 - lo2) >> 1);
    int c = 0;
#pragma unroll
    for (int s = 0; s < NS; ++s) c += (int)__popcll(__ballot(e[s] <= mid));
    if (c == KNN) { hi2 = mid; break; }   // exact set found
    if (c > KNN) hi2 = mid; else lo2 = mid + 1;
  }
  const unsigned T = hi2;
  float r0=0.f,r1=0.f,r2=0.f,r3=0.f,r4=0.f,r5=0.f;
  int base2 = 0;
#pragma unroll
  for (int s = 0; s < NS; ++s) {
    bool p = (e[s] <= T);
    unsigned long long m = __ballot(p);
    if (p) {
      int pos = base2 + (int)__popcll(m & lmask);
      if (pos < KNN) {
        int n = IDXL[s*64 + lane];
        SEL[pos] = n;
        dst[pos] = (unsigned short)n;
        float dx = Pb[n*3+0]-kx, dy = Pb[n*3+1]-ky, dz = Pb[n*3+2]-kz;
        r0 += dx; r1 += dy; r2 += dz;
        r3 += dx*dx; r4 += dy*dy; r5 += dz*dz;
      }
    }
    base2 += (int)__popcll(m);
  }
#pragma unroll
  for (int off = 32; off > 0; off >>= 1) {
    r0 += __shfl_down(r0, off); r1 += __shfl_down(r1, off);
    r2 += __shfl_down(r2, off); r3 += __shfl_down(r3, off);
    r4 += __shfl_down(r4, off); r5 += __shfl_down(r5, off);
  }
  if (lane == 0) {
    atomicAdd(&accs[0], r0); atomicAdd(&accs[1], r1); atomicAdd(&accs[2], r2);
    atomicAdd(&accs[64], r3); atomicAdd(&accs[65], r4); atomicAdd(&accs[66], r5);
  }
}

__device__ __forceinline__ void dispatch_select(
    const unsigned* VAL, const int* IDXL, int mcount, unsigned hib, unsigned lob,
    int lane, const float* Pb, float kx, float ky, float kz,
    unsigned short* dst, int* SEL, float* accs) {
  if (mcount <= 64)
    select_emit<1>(VAL, IDXL, mcount, hib, lob, lane, Pb, kx, ky, kz, dst, SEL, accs);
  else if (mcount <= 128)
    select_emit<2>(VAL, IDXL, mcount, hib, lob, lane, Pb, kx, ky, kz, dst, SEL, accs);
  else
    select_emit<5>(VAL, IDXL, mcount, hib, lob, lane, Pb, kx, ky, kz, dst, SEL, accs);
}

// ====== topk (blocks < 4096): TWO queries per block ======
// ====== prep tail (blocks >= 4096): frag-major weights + attA ======
// W2/W3 staged with pi-permuted K so that C-layout -> operand-frag conversion
// in main_kernel is in-lane: k_orig = 32*(kc>>1)+16*(kc&1)+4*h+(j&3)+8*(j>>2).
// W3 staged TRANSPOSED (as B operand: col = out-channel o).
__global__ __launch_bounds__(256, 6) void topk_kernel(
    const float* __restrict__ keys, const float* __restrict__ points,
    const float* __restrict__ feats,
    const float* __restrict__ w1, const float* __restrict__ w2,
    const float* __restrict__ w3,
    const float* __restrict__ att_w, const float* __restrict__ att_q,
    unsigned short* __restrict__ idx_out, float* __restrict__ acc,
    short* __restrict__ w1f, short* __restrict__ w2f, short* __restrict__ w3f,
    float* __restrict__ attA) {
  if (blockIdx.x >= 4096) {   // ---- prep partition ----
    const int bb = blockIdx.x - 4096;
    if (bb == 128) {   // attA[c][h] = sum_d att_w[c, h*64+d]*att_q[h,d]
      const int t = threadIdx.x, c = t >> 2, h = t & 3;
      float s = 0.f;
      for (int d = 0; d < 64; ++d) s += att_w[c*256 + h*64 + d] * att_q[h*64 + d];
      attA[c*4 + h] = s;
      return;
    }
    int t = bb * 256 + threadIdx.x;   // 32768 total
    if (t < 8192) {            // W1 (A role): NH=128, K=64 natural, KC=4
      int j = t & 7, lane = (t >> 3) & 63, tk = t >> 9;
      int kc = tk & 3, tile = tk >> 2;
      int nh = tile*32 + (lane & 31), k = kc*16 + (lane >> 5)*8 + j;
      w1f[t] = (short)bf16_rne(w1[k*128 + nh]);
    } else if (t < 24576) {    // W2 (A role): NH=128, K=128 pi-permuted, KC=8
      int t2 = t - 8192;
      int j = t2 & 7, lane = (t2 >> 3) & 63, tk = t2 >> 9;
      int kc = tk & 7, tile = tk >> 3;
      int nh = tile*32 + (lane & 31);
      int k = 32*(kc>>1) + 16*(kc&1) + 4*(lane>>5) + (j&3) + 8*(j>>2);
      w2f[t2] = (short)bf16_rne(w2[k*128 + nh]);
    } else {                   // W3^T (B role): col=o (64), K=128 pi-permuted, KC=8
      int t3 = t - 24576;
      int j = t3 & 7, lane = (t3 >> 3) & 63, tk = t3 >> 9;
      int kc = tk & 7, tile = tk >> 3;
      int nh = tile*32 + (lane & 31);
      int k = 32*(kc>>1) + 16*(kc&1) + 4*(lane>>5) + (j&3) + 8*(j>>2);
      w3f[t3] = (short)bf16_rne(w3[k*64 + nh]);
    }
    return;
  }

  // ---- topk partition: queries g0=2*bid, g1=g0+1 (same batch always) ----
  __shared__ unsigned VAL[2][NCAND];
  __shared__ int IDXL[2][NCAND];
  __shared__ int SEL[2][KNN];
  __shared__ unsigned HIW[2][4], LOW[2][4];
  __shared__ int WTOT[2][4];
  __shared__ float FRED[64*33];   // merged A+B partials, stride-33
  __shared__ float FQ[64*33];
  const int tid = threadIdx.x;
  const int lane = tid & 63, wid = tid >> 6;
  const int g0 = blockIdx.x * 2, g1 = g0 + 1;
  const int b = g0 >> 11;
  const float kxA = keys[(size_t)g0*3+0], kyA = keys[(size_t)g0*3+1], kzA = keys[(size_t)g0*3+2];
  const float kxB = keys[(size_t)g1*3+0], kyB = keys[(size_t)g1*3+1], kzB = keys[(size_t)g1*3+2];
  const float* __restrict__ Pb = points + (size_t)b * NPTS * 3;

  unsigned uA[16], uB[16];
  unsigned lminA = 0xffffffffu, lminB = 0xffffffffu;
#pragma unroll
  for (int c4 = 0; c4 < 4; ++c4) {
    const float* pp = Pb + (size_t)(tid*16 + c4*4) * 3;
    float4 A = ld4u(pp), B4 = ld4u(pp + 4), C4 = ld4u(pp + 8);
    float x, y, z, dx, dy, dz;
#define DPT(slot, PX, PY, PZ)                                        \
    x = PX; y = PY; z = PZ;                                          \
    dx = x-kxA; dy = y-kyA; dz = z-kzA;                              \
    uA[slot] = __float_as_uint(dx*dx + dy*dy + dz*dz);               \
    lminA = min(lminA, uA[slot]);                                    \
    dx = x-kxB; dy = y-kyB; dz = z-kzB;                              \
    uB[slot] = __float_as_uint(dx*dx + dy*dy + dz*dz);               \
    lminB = min(lminB, uB[slot]);
    DPT(c4*4+0, A.x,  A.y,  A.z)
    DPT(c4*4+1, A.w,  B4.x, B4.y)
    DPT(c4*4+2, B4.z, B4.w, C4.x)
    DPT(c4*4+3, C4.y, C4.z, C4.w)
#undef DPT
  }
  unsigned wloA = lminA, whiA = lminA, wloB = lminB, whiB = lminB;
#pragma unroll
  for (int off = 1; off < 64; off <<= 1) {
    unsigned a0 = (unsigned)__shfl_xor((int)wloA, off);
    unsigned a1 = (unsigned)__shfl_xor((int)whiA, off);
    unsigned b0 = (unsigned)__shfl_xor((int)wloB, off);
    unsigned b1 = (unsigned)__shfl_xor((int)whiB, off);
    wloA = min(wloA, a0); whiA = max(whiA, a1);
    wloB = min(wloB, b0); whiB = max(whiB, b1);
  }
  unsigned hiA, hiB;
  {
    unsigned lo = wloA, hi = whiA;
    while (lo < hi) {
      unsigned mid = lo + ((hi - lo) >> 1);
      int c = (int)__popcll(__ballot(lminA <= mid));
      if (c == KNN) { hi = mid; break; }
      if (c > KNN) hi = mid; else lo = mid + 1;
    }
    hiA = hi;
    lo = wloB; hi = whiB;
    while (lo < hi) {
      unsigned mid = lo + ((hi - lo) >> 1);
      int c = (int)__popcll(__ballot(lminB <= mid));
      if (c == KNN) { hi = mid; break; }
      if (c > KNN) hi = mid; else lo = mid + 1;
    }
    hiB = hi;
  }
  if (lane == 0) {
    HIW[0][wid] = hiA; HIW[1][wid] = hiB;
    LOW[0][wid] = wloA; LOW[1][wid] = wloB;
  }
  __syncthreads();   // S1
  const unsigned hibA = min(min(HIW[0][0],HIW[0][1]), min(HIW[0][2],HIW[0][3]));
  const unsigned hibB = min(min(HIW[1][0],HIW[1][1]), min(HIW[1][2],HIW[1][3]));
  const unsigned lobA = min(min(LOW[0][0],LOW[0][1]), min(LOW[0][2],LOW[0][3]));
  const unsigned lobB = min(min(LOW[1][0],LOW[1][1]), min(LOW[1][2],LOW[1][3]));

  int cntA = 0, cntB = 0;
#pragma unroll
  for (int j = 0; j < 16; ++j) {
    cntA += (uA[j] <= hibA) ? 1 : 0;
    cntB += (uB[j] <= hibB) ? 1 : 0;
  }
  int incA = cntA, incB = cntB;
#pragma unroll
  for (int off = 1; off < 64; off <<= 1) {
    int tA = __shfl_up(incA, off);
    int tB = __shfl_up(incB, off);
    if (lane >= off) { incA += tA; incB += tB; }
  }
  if (lane == 63) { WTOT[0][wid] = incA; WTOT[1][wid] = incB; }
  __syncthreads();   // S2
  int baseA = incA - cntA, baseB = incB - cntB;
  for (int w = 0; w < wid; ++w) { baseA += WTOT[0][w]; baseB += WTOT[1][w]; }
  {
    int pA = baseA, pB = baseB;
#pragma unroll
    for (int j = 0; j < 16; ++j) {
      if (uA[j] <= hibA) {
        if (pA < NCAND) { VAL[0][pA] = uA[j]; IDXL[0][pA] = tid*16 + j; }
        ++pA;
      }
      if (uB[j] <= hibB) {
        if (pB < NCAND) { VAL[1][pB] = uB[j]; IDXL[1][pB] = tid*16 + j; }
        ++pB;
      }
    }
  }
  __syncthreads();   // S3
  const int mcountA = min(WTOT[0][0]+WTOT[0][1]+WTOT[0][2]+WTOT[0][3], NCAND);
  const int mcountB = min(WTOT[1][0]+WTOT[1][1]+WTOT[1][2]+WTOT[1][3], NCAND);

  float* accs = &acc[(blockIdx.x & 63)*128];
  if (wid == 0) {
    dispatch_select(VAL[0], IDXL[0], mcountA, hibA, lobA, lane, Pb,
                    kxA, kyA, kzA, idx_out + (size_t)g0*KNN, SEL[0], accs);
  } else if (wid == 2) {
    dispatch_select(VAL[1], IDXL[1], mcountB, hibB, lobB, lane, Pb,
                    kxB, kyB, kzB, idx_out + (size_t)g1*KNN, SEL[1], accs);
  }
  __syncthreads();   // S4: SEL[0], SEL[1] ready

  {
    const int row = tid >> 3, chunk = tid & 7;
    const int nA = SEL[0][row], nB = SEL[1][row];
    const float* frA = feats + ((size_t)b*NPTS + nA)*CIN;
    const float* frB = feats + ((size_t)b*NPTS + nB)*CIN;
    float fs[8] = {0,0,0,0,0,0,0,0}, fq[8] = {0,0,0,0,0,0,0,0};
    if (chunk < 7) {
      float4 a0 = ld4u(frA + chunk*8), a1 = ld4u(frA + chunk*8 + 4);
      float4 b0 = ld4u(frB + chunk*8), b1 = ld4u(frB + chunk*8 + 4);
      fs[0]=a0.x+b0.x; fq[0]=a0.x*a0.x+b0.x*b0.x;
      fs[1]=a0.y+b0.y; fq[1]=a0.y*a0.y+b0.y*b0.y;
      fs[2]=a0.z+b0.z; fq[2]=a0.z*a0.z+b0.z*b0.z;
      fs[3]=a0.w+b0.w; fq[3]=a0.w*a0.w+b0.w*b0.w;
      fs[4]=a1.x+b1.x; fq[4]=a1.x*a1.x+b1.x*b1.x;
      fs[5]=a1.y+b1.y; fq[5]=a1.y*a1.y+b1.y*b1.y;
      fs[6]=a1.z+b1.z; fq[6]=a1.z*a1.z+b1.z*b1.z;
      fs[7]=a1.w+b1.w; fq[7]=a1.w*a1.w+b1.w*b1.w;
    } else {
#pragma unroll
      for (int i = 0; i < 5; ++i) {
        float va = frA[56+i], vb = frB[56+i];
        fs[i] = va + vb; fq[i] = va*va + vb*vb;
      }
    }
#pragma unroll
    for (int i = 0; i < 8; ++i) {
      FRED[(chunk*8 + i)*33 + row] = fs[i];
      FQ  [(chunk*8 + i)*33 + row] = fq[i];
    }
  }
  __syncthreads();   // S5
  if (tid < 64) {
    float s = 0.f, q2 = 0.f;
#pragma unroll
    for (int r = 0; r < 32; ++r) {
      s  += FRED[tid*33 + r];
      q2 += FQ[tid*33 + r];
    }
    if (tid < CIN) {
      atomicAdd(&accs[3 + tid], s);
      atomicAdd(&accs[64 + 3 + tid], q2);
    }
  }
}

// ---------------- main-kernel LDS offsets (bytes) ----------------
#define L_W1F 0        // 16384
#define L_W2F 16384    // 32768
#define L_W3F 49152    // 16384
#define L_SH  65536    // SAe hi frags: 4 kc * 64 * 8 shorts = 4096
#define L_SL  69632    // SAe lo frags: 4096
#define L_B1  73728    // 512
#define L_B2  74240    // 512
#define L_B3  74752    // 256
#define L_WSC 75008    // 8 waves * 512 B w-scratch (phase0: TMP [8][128] f32)
#define L_SC  79104    // f32[64]
#define L_TOT 79360    // < 80 KiB -> 2 blocks/CU

// ====== main: one wave per query, ZERO in-loop barriers ======
// chain: gather(regs) -> E-MFMA(hi/lo) -> in-reg softmax -> w bounce (512B
// per-wave LDS, intra-wave) -> G1 -> G2 -> G3(transposed) -> out-MFMA(hi/lo).
// All C->operand re-frags are in-lane cvt_pk thanks to pi-permuted weights.
__global__ __launch_bounds__(512, 4) void main_kernel(
    const float* __restrict__ keys, const float* __restrict__ points,
    const float* __restrict__ feats, const unsigned short* __restrict__ idxg,
    const short* __restrict__ w1f, const short* __restrict__ w2f,
    const short* __restrict__ w3f,
    const float* __restrict__ b1, const float* __restrict__ b2,
    const float* __restrict__ b3,
    const float* __restrict__ attAg, const float* __restrict__ accg,
    const float* __restrict__ gammav, float* __restrict__ out) {
  __shared__ __align__(16) char smem[L_TOT];
  const int tid = threadIdx.x;
  const int bid = blockIdx.x;
  const int wid = tid >> 6, lane = tid & 63;
  const int col = lane & 31, h = lane >> 5;

  // ---- phase 0 ----
  {
    // weight frags: w1f|w2f|w3f contiguous in ws = 65536 B = 4096 uint4
    const uint4* src = (const uint4*)w1f;
    uint4* dst = (uint4*)smem;
#pragma unroll
    for (int r = 0; r < 8; ++r) dst[r*512 + tid] = src[r*512 + tid];
    if (tid < 128) ((float*)(smem + L_B1))[tid] = b1[tid];
    else if (tid < 256) ((float*)(smem + L_B2))[tid-128] = b2[tid-128];
    else if (tid < 320) ((float*)(smem + L_B3))[tid-256] = b3[tid-256];
    // BN stats reduce
    float* TMP = (float*)(smem + L_WSC);    // [8][128]
    {
      int c = tid & 63, p = tid >> 6;
      float s = 0.f, s2 = 0.f;
      for (int k = p; k < 64; k += 8) {
        s += accg[k*128 + c]; s2 += accg[k*128 + 64 + c];
      }
      TMP[p*128 + c] = s; TMP[p*128 + 64 + c] = s2;
    }
    __syncthreads();
    float* SCp = (float*)(smem + L_SC);
    if (tid < 64) {
      float s = 0.f, s2 = 0.f;
#pragma unroll
      for (int p = 0; p < 8; ++p) { s += TMP[p*128 + tid]; s2 += TMP[p*128 + 64 + tid]; }
      const float invR = 1.f / (float)ROWS;
      float mean = s * invR;
      float var = s2 * invR - mean * mean;
      SCp[tid] = gammav[tid] * rsqrtf(var + 1e-5f);
    }
    __syncthreads();
    // SAe hi/lo frags (B role: col=hd (<4 valid), k natural pi1)
    {
      const int s = tid >> 8;           // 0 = hi, 1 = lo
      const int kc = (tid >> 6) & 3;
      const int ln = tid & 63;
      const int hd = ln & 31;
      short* dstf = (short*)(smem + (s ? L_SL : L_SH)) + (kc*64 + ln)*8;
#pragma unroll
      for (int j = 0; j < 8; ++j) {
        const int ch = kc*16 + (ln>>5)*8 + j;
        float val = (hd < 4) ? attAg[ch*4 + hd] * SCp[ch] : 0.f;
        unsigned hb = bf16_rne(val);
        if (s) {
          float lo = val - __uint_as_float(hb << 16);
          dstf[j] = (short)bf16_rne(lo);
        } else {
          dstf[j] = (short)hb;
        }
      }
    }
    __syncthreads();
  }

  float* WS = (float*)(smem + L_WSC) + wid*128;   // per-wave [32][4]
  const short* SW1 = (const short*)(smem + L_W1F);
  const short* SW2 = (const short*)(smem + L_W2F);
  const short* SW3 = (const short*)(smem + L_W3F);
  const float* SB1 = (const float*)(smem + L_B1);
  const float* SB2 = (const float*)(smem + L_B2);

  for (int qi = 0; qi < 2; ++qi) {
    const int g = bid*8 + wid + qi*4096;
    const int b = g >> 11;
    const int n = (int)idxg[(size_t)g*KNN + col];
    const float* frow = feats + ((size_t)b*NPTS + n)*CIN;

    // ---- gather: v[kc][j] = channel kc*16 + 8h + j of neighbor n ----
    float v[4][8];
    if (h == 0) {
      const float* Pb = points + (size_t)b*NPTS*3;
      v[0][0] = Pb[n*3+0] - keys[(size_t)g*3+0];
      v[0][1] = Pb[n*3+1] - keys[(size_t)g*3+1];
      v[0][2] = Pb[n*3+2] - keys[(size_t)g*3+2];
      float4 t0 = ld4u(frow);
      v[0][3]=t0.x; v[0][4]=t0.y; v[0][5]=t0.z; v[0][6]=t0.w;
      v[0][7] = frow[4];
    } else {
      float4 a0 = ld4u(frow+5), a1 = ld4u(frow+9);
      v[0][0]=a0.x; v[0][1]=a0.y; v[0][2]=a0.z; v[0][3]=a0.w;
      v[0][4]=a1.x; v[0][5]=a1.y; v[0][6]=a1.z; v[0][7]=a1.w;
    }
#pragma unroll
    for (int kc = 1; kc < 4; ++kc) {
      const int f0 = kc*16 + 8*h - 3;
      float4 a0 = ld4u(frow+f0), a1 = ld4u(frow+f0+4);
      v[kc][0]=a0.x; v[kc][1]=a0.y; v[kc][2]=a0.z; v[kc][3]=a0.w;
      v[kc][4]=a1.x; v[kc][5]=a1.y; v[kc][6]=a1.z; v[kc][7]=a1.w;
    }

    // ---- pack act frags (hi + residual lo) ----
    ufrag ahi[4], alo[4];
#pragma unroll
    for (int kc = 0; kc < 4; ++kc)
#pragma unroll
      for (int p = 0; p < 4; ++p) {
        unsigned pk = cvtpk(v[kc][2*p], v[kc][2*p+1]);
        ahi[kc][p] = pk;
        alo[kc][p] = cvtpk(v[kc][2*p] - up_lo(pk), v[kc][2*p+1] - up_hi(pk));
      }

    // ---- E: logits [n x hd], hi/lo split (~f32 accurate) ----
    cfrag Ef = zero16();
#pragma unroll
    for (int kc = 0; kc < 4; ++kc) {
      bfrag sh = *(const bfrag*)((const short*)(smem + L_SH) + (kc*64 + lane)*8);
      bfrag sl = *(const bfrag*)((const short*)(smem + L_SL) + (kc*64 + lane)*8);
      Ef = mfma_ub(ahi[kc], sh, Ef);
      Ef = mfma_ub(alo[kc], sh, Ef);
      Ef = mfma_ub(ahi[kc], sl, Ef);
    }

    // ---- softmax over n (16 regs in-lane + one xor-32) ----
    float mx = Ef[0];
#pragma unroll
    for (int i = 1; i < 16; ++i) mx = fmaxf(mx, Ef[i]);
    mx = fmaxf(mx, __shfl_xor(mx, 32));
    float wsm[16], ssum = 0.f;
#pragma unroll
    for (int i = 0; i < 16; ++i) { wsm[i] = __expf(Ef[i] - mx); ssum += wsm[i]; }
    ssum += __shfl_xor(ssum, 32);
    const float invs = 1.f / ssum;
#pragma unroll
    for (int i = 0; i < 16; ++i) wsm[i] *= invs;

    // ---- bounce w through per-wave LDS (no barrier: intra-wave) ----
    if (col < 4) {
#pragma unroll
      for (int i = 0; i < 8; ++i) {
        const int c0 = (2*i & 3) + 8*(i >> 1);   // 0,2,8,10,16,18,24,26
        const int nA = c0 + 4*h;
        WS[nA*4 + col]     = wsm[2*i];
        WS[nA*4 + 4 + col] = wsm[2*i+1];
      }
    }
    const int hdc = col & 3;
    ufrag whi[2], wlo[2];
#pragma unroll
    for (int bb = 0; bb < 2; ++bb)
#pragma unroll
      for (int p = 0; p < 4; ++p) {
        const int c0 = (2*p & 3) + 8*(p >> 1);
        const int n0 = 16*bb + 4*h + c0;
        float r0 = WS[n0*4 + hdc], r1 = WS[n0*4 + 4 + hdc];
        unsigned pk = cvtpk(r0, r1);
        whi[bb][p] = pk;
        wlo[bb][p] = cvtpk(r0 - up_lo(pk), r1 - up_hi(pk));
      }

    // ---- GEMM1: 64 -> 128, relu, in-lane re-frag to A2 ----
    ufrag a2[8];
#pragma unroll
    for (int t = 0; t < 4; ++t) {
      cfrag acc = zero16();
#pragma unroll
      for (int kc = 0; kc < 4; ++kc) {
        bfrag wf = *(const bfrag*)(SW1 + ((t*4 + kc)*64 + lane)*8);
        acc = mfma_bu(wf, ahi[kc], acc);
      }
#pragma unroll
      for (int i = 0; i < 8; ++i) {
        const int c0 = (2*i & 3) + 8*(i >> 1);
        float2 bb2 = *(const float2*)(SB1 + t*32 + c0 + 4*h);
        float x0 = fmaxf(acc[2*i]   + bb2.x, 0.f);
        float x1 = fmaxf(acc[2*i+1] + bb2.y, 0.f);
        a2[2*t + (i>>2)][i&3] = cvtpk(x0, x1);
      }
    }

    // ---- GEMM2: 128 -> 128, relu, re-frag to A3 ----
    ufrag a3[8];
#pragma unroll
    for (int t = 0; t < 4; ++t) {
      cfrag acc = zero16();
#pragma unroll
      for (int kc = 0; kc < 8; ++kc) {
        bfrag wf = *(const bfrag*)(SW2 + ((t*8 + kc)*64 + lane)*8);
        acc = mfma_bu(wf, a2[kc], acc);
      }
#pragma unroll
      for (int i = 0; i < 8; ++i) {
        const int c0 = (2*i & 3) + 8*(i >> 1);
        float2 bb2 = *(const float2*)(SB2 + t*32 + c0 + 4*h);
        float x0 = fmaxf(acc[2*i]   + bb2.x, 0.f);
        float x1 = fmaxf(acc[2*i+1] + bb2.y, 0.f);
        a3[2*t + (i>>2)][i&3] = cvtpk(x0, x1);
      }
    }

    // ---- GEMM3 (transposed: D3'[n][o] = act2^T * W3^T) + out-MFMA ----
#pragma unroll
    for (int t = 0; t < 2; ++t) {
      cfrag acc = zero16();
#pragma unroll
      for (int kc = 0; kc < 8; ++kc) {
        bfrag wf = *(const bfrag*)(SW3 + ((t*8 + kc)*64 + lane)*8);
        acc = mfma_ub(a3[kc], wf, acc);
      }
      const float bz = ((const float*)(smem + L_B3))[t*32 + col];
#pragma unroll
      for (int i = 0; i < 16; ++i) acc[i] += bz;
      // lat^T re-frag (hi + lo)
      ufrag lh[2], ll[2];
#pragma unroll
      for (int i = 0; i < 8; ++i) {
        unsigned pk = cvtpk(acc[2*i], acc[2*i+1]);
        lh[i>>2][i&3] = pk;
        ll[i>>2][i&3] = cvtpk(acc[2*i] - up_lo(pk), acc[2*i+1] - up_hi(pk));
      }
      cfrag og = zero16();
#pragma unroll
      for (int bb = 0; bb < 2; ++bb) og = mfma_uu(lh[bb], whi[bb], og);
#pragma unroll
      for (int bb = 0; bb < 2; ++bb) og = mfma_uu(ll[bb], whi[bb], og);
#pragma unroll
      for (int bb = 0; bb < 2; ++bb) og = mfma_uu(lh[bb], wlo[bb], og);
      if (col < 4) {
        float* op = out + (size_t)g*256 + t*128 + col;
#pragma unroll
        for (int i = 0; i < 16; ++i) {
          const int orow = (i&3) + 8*(i>>2) + 4*h;
          op[orow*4] = og[i];
        }
      }
    }
  }
}

extern "C" void kernel_launch(void* const* d_in, const int* in_sizes, int n_in,
                              void* d_out, int out_size, void* d_ws, size_t ws_size,
                              hipStream_t stream) {
  const float* keys   = (const float*)d_in[0];
  const float* points = (const float*)d_in[1];
  const float* feats  = (const float*)d_in[2];
  const float* nx_w1  = (const float*)d_in[3];
  const float* nx_b1  = (const float*)d_in[4];
  const float* nx_w2  = (const float*)d_in[5];
  const float* nx_b2  = (const float*)d_in[6];
  const float* nx_w3  = (const float*)d_in[7];
  const float* nx_b3  = (const float*)d_in[8];
  // sx_w*/sx_b* (9..14), att_b (16), bn_beta (19): n-constant in softmax -> dead
  const float* att_w  = (const float*)d_in[15];
  const float* att_q  = (const float*)d_in[17];
  const float* gamma  = (const float*)d_in[18];
  float* out = (float*)d_out;

  char* ws = (char*)d_ws;
  unsigned short* idxp = (unsigned short*)(ws + OFF_IDX);
  float* acc  = (float*)(ws + OFF_ACC);
  float* attA = (float*)(ws + OFF_ATTA);
  short* w1f  = (short*)(ws + OFF_W1F);
  short* w2f  = (short*)(ws + OFF_W2F);
  short* w3f  = (short*)(ws + OFF_W3F);

  hipMemsetAsync(acc, 0, 32768, stream);
  topk_kernel<<<4096 + 129, 256, 0, stream>>>(keys, points, feats,
      nx_w1, nx_w2, nx_w3, att_w, att_q, idxp, acc, w1f, w2f, w3f, attA);
  main_kernel<<<512, 512, 0, stream>>>(keys, points, feats, idxp,
      w1f, w2f, w3f, nx_b1, nx_b2, nx_b3, attA, acc, gamma, out);
}

// Round 4
// 162.024 us; speedup vs baseline: 1.2373x; 1.0314x over previous
//
#include <hip/hip_runtime.h>
#include <math.h>

#define BATCH 4
#define KQ    2048
#define NPTS  4096
#define CIN   61
#define KNN   32
#define ROWS  (BATCH*KQ*KNN)   // 262144

// ---------------- ws layout (bytes) ----------------
#define OFF_IDX  0         // u16 [262144] = 524288
#define OFF_ACC  524288    // f32 [64 slots][128] = 32768 (sum 0..63 | sumsq 64..127)
#define OFF_ATTA 557056    // f32[256]
#define OFF_W1F  558080    // bf16 frag-major = 16384
#define OFF_W2F  574464    // 32768
#define OFF_W3F  607232    // 16384 (end 623616)

typedef __attribute__((ext_vector_type(8)))  short bfrag;     // 8 bf16
typedef __attribute__((ext_vector_type(4)))  unsigned ufrag;  // 8 bf16 as 4 u32
typedef __attribute__((ext_vector_type(16))) float cfrag;     // 32x32 acc

__device__ __forceinline__ unsigned short bf16_rne(float x) {
  unsigned u = __float_as_uint(x);
  unsigned r = u + 0x7fffu + ((u >> 16) & 1u);
  return (unsigned short)(r >> 16);
}
__device__ __forceinline__ float4 ld4u(const float* p) {  // 4B-aligned vec load
  float4 r; __builtin_memcpy(&r, p, 16); return r;
}
__device__ __forceinline__ unsigned cvtpk(float lo, float hi) {
  unsigned r;
  asm("v_cvt_pk_bf16_f32 %0, %1, %2" : "=v"(r) : "v"(lo), "v"(hi));
  return r;
}
__device__ __forceinline__ float up_lo(unsigned pk) { return __uint_as_float(pk << 16); }
__device__ __forceinline__ float up_hi(unsigned pk) { return __uint_as_float(pk & 0xffff0000u); }

__device__ __forceinline__ cfrag zero16() {
  cfrag z;
#pragma unroll
  for (int i = 0; i < 16; ++i) z[i] = 0.f;
  return z;
}
__device__ __forceinline__ cfrag mfma_bu(bfrag a, ufrag b, cfrag c) {
  return __builtin_amdgcn_mfma_f32_32x32x16_bf16(a, __builtin_bit_cast(bfrag, b), c, 0, 0, 0);
}
__device__ __forceinline__ cfrag mfma_ub(ufrag a, bfrag b, cfrag c) {
  return __builtin_amdgcn_mfma_f32_32x32x16_bf16(__builtin_bit_cast(bfrag, a), b, c, 0, 0, 0);
}
__device__ __forceinline__ cfrag mfma_uu(ufrag a, ufrag b, cfrag c) {
  return __builtin_amdgcn_mfma_f32_32x32x16_bf16(__builtin_bit_cast(bfrag, a), __builtin_bit_cast(bfrag, b), c, 0, 0, 0);
}

#define NCAND 384   // candidate cap per query (single-wave bound => E ~175)

// exact select of KNN smallest among mcount candidates (NS = ceil(mcount/64)).
template<int NS>
__device__ __forceinline__ void select_emit(
    const unsigned* __restrict__ VAL, const int* __restrict__ IDXL,
    int mcount, unsigned hib, unsigned lob, int lane,
    const float* __restrict__ Pb, float kx, float ky, float kz,
    unsigned short* __restrict__ dst, int* __restrict__ SEL,
    float* __restrict__ accs) {
  const unsigned long long lmask = (1ull << lane) - 1ull;
  unsigned e[NS];
#pragma unroll
  for (int s = 0; s < NS; ++s) {
    int ei = s*64 + lane;
    e[s] = (ei < mcount) ? VAL[ei] : 0xffffffffu;
  }
  unsigned lo2 = lob, hi2 = hib;   // invariant: count(<= hi2) >= KNN
  while (lo2 < hi2) {
    unsigned mid = lo2 + ((hi2 - lo2) >> 1);
    int c = 0;
#pragma unroll
    for (int s = 0; s < NS; ++s) c += (int)__popcll(__ballot(e[s] <= mid));
    if (c == KNN) { hi2 = mid; break; }   // exact set found
    if (c > KNN) hi2 = mid; else lo2 = mid + 1;
  }
  const unsigned T = hi2;
  float r0=0.f,r1=0.f,r2=0.f,r3=0.f,r4=0.f,r5=0.f;
  int base2 = 0;
#pragma unroll
  for (int s = 0; s < NS; ++s) {
    bool p = (e[s] <= T);
    unsigned long long m = __ballot(p);
    if (p) {
      int pos = base2 + (int)__popcll(m & lmask);
      if (pos < KNN) {
        int n = IDXL[s*64 + lane];
        SEL[pos] = n;
        dst[pos] = (unsigned short)n;
        float dx = Pb[n*3+0]-kx, dy = Pb[n*3+1]-ky, dz = Pb[n*3+2]-kz;
        r0 += dx; r1 += dy; r2 += dz;
        r3 += dx*dx; r4 += dy*dy; r5 += dz*dz;
      }
    }
    base2 += (int)__popcll(m);
  }
#pragma unroll
  for (int off = 32; off > 0; off >>= 1) {
    r0 += __shfl_down(r0, off); r1 += __shfl_down(r1, off);
    r2 += __shfl_down(r2, off); r3 += __shfl_down(r3, off);
    r4 += __shfl_down(r4, off); r5 += __shfl_down(r5, off);
  }
  if (lane == 0) {
    atomicAdd(&accs[0], r0); atomicAdd(&accs[1], r1); atomicAdd(&accs[2], r2);
    atomicAdd(&accs[64], r3); atomicAdd(&accs[65], r4); atomicAdd(&accs[66], r5);
  }
}

__device__ __forceinline__ void dispatch_select(
    const unsigned* VAL, const int* IDXL, int mcount, unsigned hib, unsigned lob,
    int lane, const float* Pb, float kx, float ky, float kz,
    unsigned short* dst, int* SEL, float* accs) {
  if (mcount <= 64)
    select_emit<1>(VAL, IDXL, mcount, hib, lob, lane, Pb, kx, ky, kz, dst, SEL, accs);
  else if (mcount <= 128)
    select_emit<2>(VAL, IDXL, mcount, hib, lob, lane, Pb, kx, ky, kz, dst, SEL, accs);
  else if (mcount <= 192)
    select_emit<3>(VAL, IDXL, mcount, hib, lob, lane, Pb, kx, ky, kz, dst, SEL, accs);
  else
    select_emit<6>(VAL, IDXL, mcount, hib, lob, lane, Pb, kx, ky, kz, dst, SEL, accs);
}

// ====== topk (blocks < 2048): FOUR queries per block, wave w owns query w ====
// ====== prep tail (blocks >= 2048): frag-major weights + attA ======
// W2/W3 staged with pi-permuted K so that C-layout -> operand-frag conversion
// in main_kernel is in-lane: k_orig = 32*(kc>>1)+16*(kc&1)+4*h+(j&3)+8*(j>>2).
// W3 staged TRANSPOSED (as B operand: col = out-channel o).
__global__ __launch_bounds__(256, 4) void topk_kernel(
    const float* __restrict__ keys, const float* __restrict__ points,
    const float* __restrict__ feats,
    const float* __restrict__ w1, const float* __restrict__ w2,
    const float* __restrict__ w3,
    const float* __restrict__ att_w, const float* __restrict__ att_q,
    unsigned short* __restrict__ idx_out, float* __restrict__ acc,
    short* __restrict__ w1f, short* __restrict__ w2f, short* __restrict__ w3f,
    float* __restrict__ attA) {
  if (blockIdx.x >= 2048) {   // ---- prep partition ----
    const int bb = blockIdx.x - 2048;
    if (bb == 128) {   // attA[c][h] = sum_d att_w[c, h*64+d]*att_q[h,d]
      const int t = threadIdx.x, c = t >> 2, h = t & 3;
      float s = 0.f;
      for (int d = 0; d < 64; ++d) s += att_w[c*256 + h*64 + d] * att_q[h*64 + d];
      attA[c*4 + h] = s;
      return;
    }
    int t = bb * 256 + threadIdx.x;   // 32768 total
    if (t < 8192) {            // W1 (A role): NH=128, K=64 natural, KC=4
      int j = t & 7, lane = (t >> 3) & 63, tk = t >> 9;
      int kc = tk & 3, tile = tk >> 2;
      int nh = tile*32 + (lane & 31), k = kc*16 + (lane >> 5)*8 + j;
      w1f[t] = (short)bf16_rne(w1[k*128 + nh]);
    } else if (t < 24576) {    // W2 (A role): NH=128, K=128 pi-permuted, KC=8
      int t2 = t - 8192;
      int j = t2 & 7, lane = (t2 >> 3) & 63, tk = t2 >> 9;
      int kc = tk & 7, tile = tk >> 3;
      int nh = tile*32 + (lane & 31);
      int k = 32*(kc>>1) + 16*(kc&1) + 4*(lane>>5) + (j&3) + 8*(j>>2);
      w2f[t2] = (short)bf16_rne(w2[k*128 + nh]);
    } else {                   // W3^T (B role): col=o (64), K=128 pi-permuted, KC=8
      int t3 = t - 24576;
      int j = t3 & 7, lane = (t3 >> 3) & 63, tk = t3 >> 9;
      int kc = tk & 7, tile = tk >> 3;
      int nh = tile*32 + (lane & 31);
      int k = 32*(kc>>1) + 16*(kc&1) + 4*(lane>>5) + (j&3) + 8*(j>>2);
      w3f[t3] = (short)bf16_rne(w3[k*64 + nh]);
    }
    return;
  }

  // ---- topk partition: queries g0..g0+3 (same batch: 2048 % 4 == 0) ----
  __shared__ unsigned VAL[4][NCAND];
  __shared__ int IDXL[4][NCAND];
  __shared__ int SEL[4][KNN];
  __shared__ unsigned HIB[4];
  __shared__ int WTOT[4][4];   // [query][wave]
  __shared__ float FRED[64*33];   // merged 4-query partials, stride-33
  __shared__ float FQ[64*33];
  const int tid = threadIdx.x;
  const int lane = tid & 63, wid = tid >> 6;
  const int g0 = blockIdx.x * 4;
  const int b = g0 >> 11;
  // 4 query keys: 12 contiguous floats, 16B aligned (g0 % 4 == 0)
  float4 K0 = ld4u(keys + (size_t)g0*3);
  float4 K1 = ld4u(keys + (size_t)g0*3 + 4);
  float4 K2 = ld4u(keys + (size_t)g0*3 + 8);
  const float kx0=K0.x, ky0=K0.y, kz0=K0.z;
  const float kx1=K0.w, ky1=K1.x, kz1=K1.y;
  const float kx2=K1.z, ky2=K1.w, kz2=K2.x;
  const float kx3=K2.y, ky3=K2.z, kz3=K2.w;
  const float* __restrict__ Pb = points + (size_t)b * NPTS * 3;

  // distances for 4 queries: 16 contiguous points/thread, shared loads
  unsigned u0[16], u1[16], u2[16], u3[16];
  unsigned lm0 = 0xffffffffu, lm1 = 0xffffffffu, lm2 = 0xffffffffu, lm3 = 0xffffffffu;
#pragma unroll
  for (int c4 = 0; c4 < 4; ++c4) {
    const float* pp = Pb + (size_t)(tid*16 + c4*4) * 3;
    float4 A = ld4u(pp), B4 = ld4u(pp + 4), C4 = ld4u(pp + 8);
    float x, y, z, dx, dy, dz;
#define DPT(slot, PX, PY, PZ)                                        \
    x = PX; y = PY; z = PZ;                                          \
    dx = x-kx0; dy = y-ky0; dz = z-kz0;                              \
    u0[slot] = __float_as_uint(dx*dx + dy*dy + dz*dz);               \
    lm0 = min(lm0, u0[slot]);                                        \
    dx = x-kx1; dy = y-ky1; dz = z-kz1;                              \
    u1[slot] = __float_as_uint(dx*dx + dy*dy + dz*dz);               \
    lm1 = min(lm1, u1[slot]);                                        \
    dx = x-kx2; dy = y-ky2; dz = z-kz2;                              \
    u2[slot] = __float_as_uint(dx*dx + dy*dy + dz*dz);               \
    lm2 = min(lm2, u2[slot]);                                        \
    dx = x-kx3; dy = y-ky3; dz = z-kz3;                              \
    u3[slot] = __float_as_uint(dx*dx + dy*dy + dz*dz);               \
    lm3 = min(lm3, u3[slot]);
    DPT(c4*4+0, A.x,  A.y,  A.z)
    DPT(c4*4+1, A.w,  B4.x, B4.y)
    DPT(c4*4+2, B4.z, B4.w, C4.x)
    DPT(c4*4+3, C4.y, C4.z, C4.w)
#undef DPT
  }

  // wave w bounds its OWN query w using its lane-mins (valid global upper
  // bound: each lane-min is a distinct point). Early-exit at count==KNN.
  const unsigned lmw = (wid == 0) ? lm0 : (wid == 1) ? lm1 : (wid == 2) ? lm2 : lm3;
  unsigned wlo = lmw, whi = lmw;
#pragma unroll
  for (int off = 1; off < 64; off <<= 1) {
    unsigned a0 = (unsigned)__shfl_xor((int)wlo, off);
    unsigned a1 = (unsigned)__shfl_xor((int)whi, off);
    wlo = min(wlo, a0); whi = max(whi, a1);
  }
  {
    unsigned lo = wlo, hi = whi;
    while (lo < hi) {
      unsigned mid = lo + ((hi - lo) >> 1);
      int c = (int)__popcll(__ballot(lmw <= mid));
      if (c == KNN) { hi = mid; break; }
      if (c > KNN) hi = mid; else lo = mid + 1;
    }
    if (lane == 0) HIB[wid] = hi;
  }
  __syncthreads();   // S1
  const unsigned hb0 = HIB[0], hb1 = HIB[1], hb2 = HIB[2], hb3 = HIB[3];

  // counts + 4 interleaved exclusive scans
  int c0 = 0, c1 = 0, c2 = 0, c3 = 0;
#pragma unroll
  for (int j = 0; j < 16; ++j) {
    c0 += (u0[j] <= hb0) ? 1 : 0;
    c1 += (u1[j] <= hb1) ? 1 : 0;
    c2 += (u2[j] <= hb2) ? 1 : 0;
    c3 += (u3[j] <= hb3) ? 1 : 0;
  }
  int i0 = c0, i1 = c1, i2 = c2, i3 = c3;
#pragma unroll
  for (int off = 1; off < 64; off <<= 1) {
    int t0 = __shfl_up(i0, off), t1 = __shfl_up(i1, off);
    int t2 = __shfl_up(i2, off), t3 = __shfl_up(i3, off);
    if (lane >= off) { i0 += t0; i1 += t1; i2 += t2; i3 += t3; }
  }
  if (lane == 63) {
    WTOT[0][wid] = i0; WTOT[1][wid] = i1; WTOT[2][wid] = i2; WTOT[3][wid] = i3;
  }
  __syncthreads();   // S2
  int p0 = i0 - c0, p1 = i1 - c1, p2 = i2 - c2, p3 = i3 - c3;
  for (int w = 0; w < wid; ++w) {
    p0 += WTOT[0][w]; p1 += WTOT[1][w]; p2 += WTOT[2][w]; p3 += WTOT[3][w];
  }
#pragma unroll
  for (int j = 0; j < 16; ++j) {
    const int n = tid*16 + j;
    if (u0[j] <= hb0) { if (p0 < NCAND) { VAL[0][p0] = u0[j]; IDXL[0][p0] = n; } ++p0; }
    if (u1[j] <= hb1) { if (p1 < NCAND) { VAL[1][p1] = u1[j]; IDXL[1][p1] = n; } ++p1; }
    if (u2[j] <= hb2) { if (p2 < NCAND) { VAL[2][p2] = u2[j]; IDXL[2][p2] = n; } ++p2; }
    if (u3[j] <= hb3) { if (p3 < NCAND) { VAL[3][p3] = u3[j]; IDXL[3][p3] = n; } ++p3; }
  }
  __syncthreads();   // S3

  // exact select: wave w -> query w (all 4 waves busy)
  float* accs = &acc[(blockIdx.x & 63)*128];
  {
    const int mcount = min(WTOT[wid][0]+WTOT[wid][1]+WTOT[wid][2]+WTOT[wid][3], NCAND);
    const unsigned hibw = (wid == 0) ? hb0 : (wid == 1) ? hb1 : (wid == 2) ? hb2 : hb3;
    const float kxw = (wid == 0) ? kx0 : (wid == 1) ? kx1 : (wid == 2) ? kx2 : kx3;
    const float kyw = (wid == 0) ? ky0 : (wid == 1) ? ky1 : (wid == 2) ? ky2 : ky3;
    const float kzw = (wid == 0) ? kz0 : (wid == 1) ? kz1 : (wid == 2) ? kz2 : kz3;
    dispatch_select(VAL[wid], IDXL[wid], mcount, hibw, wlo, lane, Pb,
                    kxw, kyw, kzw, idx_out + (size_t)(g0 + wid)*KNN, SEL[wid], accs);
  }
  __syncthreads();   // S4: SEL ready

  // feats BN stats merged over 4 queries: rowslot=tid>>3 (32), chunk=tid&7
  {
    const int row = tid >> 3, chunk = tid & 7;
    const int nA = SEL[0][row], nB = SEL[1][row];
    const int nC = SEL[2][row], nD = SEL[3][row];
    const float* frA = feats + ((size_t)b*NPTS + nA)*CIN;
    const float* frB = feats + ((size_t)b*NPTS + nB)*CIN;
    const float* frC = feats + ((size_t)b*NPTS + nC)*CIN;
    const float* frD = feats + ((size_t)b*NPTS + nD)*CIN;
    float fs[8] = {0,0,0,0,0,0,0,0}, fq[8] = {0,0,0,0,0,0,0,0};
    if (chunk < 7) {
      const float* fr[4] = {frA, frB, frC, frD};
#pragma unroll
      for (int qq = 0; qq < 4; ++qq) {
        float4 a0 = ld4u(fr[qq] + chunk*8), a1 = ld4u(fr[qq] + chunk*8 + 4);
        fs[0]+=a0.x; fq[0]+=a0.x*a0.x; fs[1]+=a0.y; fq[1]+=a0.y*a0.y;
        fs[2]+=a0.z; fq[2]+=a0.z*a0.z; fs[3]+=a0.w; fq[3]+=a0.w*a0.w;
        fs[4]+=a1.x; fq[4]+=a1.x*a1.x; fs[5]+=a1.y; fq[5]+=a1.y*a1.y;
        fs[6]+=a1.z; fq[6]+=a1.z*a1.z; fs[7]+=a1.w; fq[7]+=a1.w*a1.w;
      }
    } else {
#pragma unroll
      for (int i = 0; i < 5; ++i) {
        float va = frA[56+i], vb = frB[56+i], vc = frC[56+i], vd = frD[56+i];
        fs[i] = va + vb + vc + vd;
        fq[i] = va*va + vb*vb + vc*vc + vd*vd;
      }
    }
#pragma unroll
    for (int i = 0; i < 8; ++i) {
      FRED[(chunk*8 + i)*33 + row] = fs[i];
      FQ  [(chunk*8 + i)*33 + row] = fq[i];
    }
  }
  __syncthreads();   // S5
  if (tid < 64) {
    float s = 0.f, q2 = 0.f;
#pragma unroll
    for (int r = 0; r < 32; ++r) {
      s  += FRED[tid*33 + r];
      q2 += FQ[tid*33 + r];
    }
    if (tid < CIN) {
      atomicAdd(&accs[3 + tid], s);
      atomicAdd(&accs[64 + 3 + tid], q2);
    }
  }
}

// ---------------- main-kernel LDS offsets (bytes) ----------------
#define L_W1F 0        // 16384
#define L_W2F 16384    // 32768
#define L_W3F 49152    // 16384
#define L_SH  65536    // SAe hi frags: 4 kc * 64 * 8 shorts = 4096
#define L_SL  69632    // SAe lo frags: 4096
#define L_B1  73728    // 512
#define L_B2  74240    // 512
#define L_B3  74752    // 256
#define L_WSC 75008    // 8 waves * 512 B w-scratch (phase0: TMP [8][128] f32)
#define L_SC  79104    // f32[64]
#define L_TOT 79360    // < 80 KiB -> 2 blocks/CU

// ====== main: one wave per query, ZERO in-loop barriers ======
// chain: gather(regs) -> E-MFMA(hi/lo) -> in-reg softmax -> w bounce (512B
// per-wave LDS, intra-wave) -> G1 -> G2 -> G3(transposed) -> out-MFMA(hi/lo).
// All C->operand re-frags are in-lane cvt_pk thanks to pi-permuted weights.
__global__ __launch_bounds__(512, 4) void main_kernel(
    const float* __restrict__ keys, const float* __restrict__ points,
    const float* __restrict__ feats, const unsigned short* __restrict__ idxg,
    const short* __restrict__ w1f, const short* __restrict__ w2f,
    const short* __restrict__ w3f,
    const float* __restrict__ b1, const float* __restrict__ b2,
    const float* __restrict__ b3,
    const float* __restrict__ attAg, const float* __restrict__ accg,
    const float* __restrict__ gammav, float* __restrict__ out) {
  __shared__ __align__(16) char smem[L_TOT];
  const int tid = threadIdx.x;
  const int bid = blockIdx.x;
  const int wid = tid >> 6, lane = tid & 63;
  const int col = lane & 31, h = lane >> 5;

  // ---- phase 0 ----
  {
    // weight frags: w1f|w2f|w3f contiguous in ws = 65536 B = 4096 uint4
    const uint4* src = (const uint4*)w1f;
    uint4* dst = (uint4*)smem;
#pragma unroll
    for (int r = 0; r < 8; ++r) dst[r*512 + tid] = src[r*512 + tid];
    if (tid < 128) ((float*)(smem + L_B1))[tid] = b1[tid];
    else if (tid < 256) ((float*)(smem + L_B2))[tid-128] = b2[tid-128];
    else if (tid < 320) ((float*)(smem + L_B3))[tid-256] = b3[tid-256];
    // BN stats reduce
    float* TMP = (float*)(smem + L_WSC);    // [8][128]
    {
      int c = tid & 63, p = tid >> 6;
      float s = 0.f, s2 = 0.f;
      for (int k = p; k < 64; k += 8) {
        s += accg[k*128 + c]; s2 += accg[k*128 + 64 + c];
      }
      TMP[p*128 + c] = s; TMP[p*128 + 64 + c] = s2;
    }
    __syncthreads();
    float* SCp = (float*)(smem + L_SC);
    if (tid < 64) {
      float s = 0.f, s2 = 0.f;
#pragma unroll
      for (int p = 0; p < 8; ++p) { s += TMP[p*128 + tid]; s2 += TMP[p*128 + 64 + tid]; }
      const float invR = 1.f / (float)ROWS;
      float mean = s * invR;
      float var = s2 * invR - mean * mean;
      SCp[tid] = gammav[tid] * rsqrtf(var + 1e-5f);
    }
    __syncthreads();
    // SAe hi/lo frags (B role: col=hd (<4 valid), k natural pi1)
    {
      const int s = tid >> 8;           // 0 = hi, 1 = lo
      const int kc = (tid >> 6) & 3;
      const int ln = tid & 63;
      const int hd = ln & 31;
      short* dstf = (short*)(smem + (s ? L_SL : L_SH)) + (kc*64 + ln)*8;
#pragma unroll
      for (int j = 0; j < 8; ++j) {
        const int ch = kc*16 + (ln>>5)*8 + j;
        float val = (hd < 4) ? attAg[ch*4 + hd] * SCp[ch] : 0.f;
        unsigned hb = bf16_rne(val);
        if (s) {
          float lo = val - __uint_as_float(hb << 16);
          dstf[j] = (short)bf16_rne(lo);
        } else {
          dstf[j] = (short)hb;
        }
      }
    }
    __syncthreads();
  }

  float* WS = (float*)(smem + L_WSC) + wid*128;   // per-wave [32][4]
  const short* SW1 = (const short*)(smem + L_W1F);
  const short* SW2 = (const short*)(smem + L_W2F);
  const short* SW3 = (const short*)(smem + L_W3F);
  const float* SB1 = (const float*)(smem + L_B1);
  const float* SB2 = (const float*)(smem + L_B2);

  for (int qi = 0; qi < 2; ++qi) {
    const int g = bid*8 + wid + qi*4096;
    const int b = g >> 11;
    const int n = (int)idxg[(size_t)g*KNN + col];
    const float* frow = feats + ((size_t)b*NPTS + n)*CIN;

    // ---- gather: v[kc][j] = channel kc*16 + 8h + j of neighbor n ----
    float v[4][8];
    if (h == 0) {
      const float* Pb = points + (size_t)b*NPTS*3;
      v[0][0] = Pb[n*3+0] - keys[(size_t)g*3+0];
      v[0][1] = Pb[n*3+1] - keys[(size_t)g*3+1];
      v[0][2] = Pb[n*3+2] - keys[(size_t)g*3+2];
      float4 t0 = ld4u(frow);
      v[0][3]=t0.x; v[0][4]=t0.y; v[0][5]=t0.z; v[0][6]=t0.w;
      v[0][7] = frow[4];
    } else {
      float4 a0 = ld4u(frow+5), a1 = ld4u(frow+9);
      v[0][0]=a0.x; v[0][1]=a0.y; v[0][2]=a0.z; v[0][3]=a0.w;
      v[0][4]=a1.x; v[0][5]=a1.y; v[0][6]=a1.z; v[0][7]=a1.w;
    }
#pragma unroll
    for (int kc = 1; kc < 4; ++kc) {
      const int f0 = kc*16 + 8*h - 3;
      float4 a0 = ld4u(frow+f0), a1 = ld4u(frow+f0+4);
      v[kc][0]=a0.x; v[kc][1]=a0.y; v[kc][2]=a0.z; v[kc][3]=a0.w;
      v[kc][4]=a1.x; v[kc][5]=a1.y; v[kc][6]=a1.z; v[kc][7]=a1.w;
    }

    // ---- pack act frags (hi + residual lo) ----
    ufrag ahi[4], alo[4];
#pragma unroll
    for (int kc = 0; kc < 4; ++kc)
#pragma unroll
      for (int p = 0; p < 4; ++p) {
        unsigned pk = cvtpk(v[kc][2*p], v[kc][2*p+1]);
        ahi[kc][p] = pk;
        alo[kc][p] = cvtpk(v[kc][2*p] - up_lo(pk), v[kc][2*p+1] - up_hi(pk));
      }

    // ---- E: logits [n x hd], hi/lo split (~f32 accurate) ----
    cfrag Ef = zero16();
#pragma unroll
    for (int kc = 0; kc < 4; ++kc) {
      bfrag sh = *(const bfrag*)((const short*)(smem + L_SH) + (kc*64 + lane)*8);
      bfrag sl = *(const bfrag*)((const short*)(smem + L_SL) + (kc*64 + lane)*8);
      Ef = mfma_ub(ahi[kc], sh, Ef);
      Ef = mfma_ub(alo[kc], sh, Ef);
      Ef = mfma_ub(ahi[kc], sl, Ef);
    }

    // ---- softmax over n (16 regs in-lane + one xor-32) ----
    float mx = Ef[0];
#pragma unroll
    for (int i = 1; i < 16; ++i) mx = fmaxf(mx, Ef[i]);
    mx = fmaxf(mx, __shfl_xor(mx, 32));
    float wsm[16], ssum = 0.f;
#pragma unroll
    for (int i = 0; i < 16; ++i) { wsm[i] = __expf(Ef[i] - mx); ssum += wsm[i]; }
    ssum += __shfl_xor(ssum, 32);
    const float invs = 1.f / ssum;
#pragma unroll
    for (int i = 0; i < 16; ++i) wsm[i] *= invs;

    // ---- bounce w through per-wave LDS (no barrier: intra-wave) ----
    if (col < 4) {
#pragma unroll
      for (int i = 0; i < 8; ++i) {
        const int c0 = (2*i & 3) + 8*(i >> 1);   // 0,2,8,10,16,18,24,26
        const int nA = c0 + 4*h;
        WS[nA*4 + col]     = wsm[2*i];
        WS[nA*4 + 4 + col] = wsm[2*i+1];
      }
    }
    const int hdc = col & 3;
    ufrag whi[2], wlo[2];
#pragma unroll
    for (int bb = 0; bb < 2; ++bb)
#pragma unroll
      for (int p = 0; p < 4; ++p) {
        const int c0 = (2*p & 3) + 8*(p >> 1);
        const int n0 = 16*bb + 4*h + c0;
        float r0 = WS[n0*4 + hdc], r1 = WS[n0*4 + 4 + hdc];
        unsigned pk = cvtpk(r0, r1);
        whi[bb][p] = pk;
        wlo[bb][p] = cvtpk(r0 - up_lo(pk), r1 - up_hi(pk));
      }

    // ---- GEMM1: 64 -> 128, relu, in-lane re-frag to A2 ----
    ufrag a2[8];
#pragma unroll
    for (int t = 0; t < 4; ++t) {
      cfrag acc = zero16();
#pragma unroll
      for (int kc = 0; kc < 4; ++kc) {
        bfrag wf = *(const bfrag*)(SW1 + ((t*4 + kc)*64 + lane)*8);
        acc = mfma_bu(wf, ahi[kc], acc);
      }
#pragma unroll
      for (int i = 0; i < 8; ++i) {
        const int c0 = (2*i & 3) + 8*(i >> 1);
        float2 bb2 = *(const float2*)(SB1 + t*32 + c0 + 4*h);
        float x0 = fmaxf(acc[2*i]   + bb2.x, 0.f);
        float x1 = fmaxf(acc[2*i+1] + bb2.y, 0.f);
        a2[2*t + (i>>2)][i&3] = cvtpk(x0, x1);
      }
    }

    // ---- GEMM2: 128 -> 128, relu, re-frag to A3 ----
    ufrag a3[8];
#pragma unroll
    for (int t = 0; t < 4; ++t) {
      cfrag acc = zero16();
#pragma unroll
      for (int kc = 0; kc < 8; ++kc) {
        bfrag wf = *(const bfrag*)(SW2 + ((t*8 + kc)*64 + lane)*8);
        acc = mfma_bu(wf, a2[kc], acc);
      }
#pragma unroll
      for (int i = 0; i < 8; ++i) {
        const int c0 = (2*i & 3) + 8*(i >> 1);
        float2 bb2 = *(const float2*)(SB2 + t*32 + c0 + 4*h);
        float x0 = fmaxf(acc[2*i]   + bb2.x, 0.f);
        float x1 = fmaxf(acc[2*i+1] + bb2.y, 0.f);
        a3[2*t + (i>>2)][i&3] = cvtpk(x0, x1);
      }
    }

    // ---- GEMM3 (transposed: D3'[n][o] = act2^T * W3^T) + out-MFMA ----
#pragma unroll
    for (int t = 0; t < 2; ++t) {
      cfrag acc = zero16();
#pragma unroll
      for (int kc = 0; kc < 8; ++kc) {
        bfrag wf = *(const bfrag*)(SW3 + ((t*8 + kc)*64 + lane)*8);
        acc = mfma_ub(a3[kc], wf, acc);
      }
      const float bz = ((const float*)(smem + L_B3))[t*32 + col];
#pragma unroll
      for (int i = 0; i < 16; ++i) acc[i] += bz;
      // lat^T re-frag (hi + lo)
      ufrag lh[2], ll[2];
#pragma unroll
      for (int i = 0; i < 8; ++i) {
        unsigned pk = cvtpk(acc[2*i], acc[2*i+1]);
        lh[i>>2][i&3] = pk;
        ll[i>>2][i&3] = cvtpk(acc[2*i] - up_lo(pk), acc[2*i+1] - up_hi(pk));
      }
      cfrag og = zero16();
#pragma unroll
      for (int bb = 0; bb < 2; ++bb) og = mfma_uu(lh[bb], whi[bb], og);
#pragma unroll
      for (int bb = 0; bb < 2; ++bb) og = mfma_uu(ll[bb], whi[bb], og);
#pragma unroll
      for (int bb = 0; bb < 2; ++bb) og = mfma_uu(lh[bb], wlo[bb], og);
      if (col < 4) {
        float* op = out + (size_t)g*256 + t*128 + col;
#pragma unroll
        for (int i = 0; i < 16; ++i) {
          const int orow = (i&3) + 8*(i>>2) + 4*h;
          op[orow*4] = og[i];
        }
      }
    }
  }
}

extern "C" void kernel_launch(void* const* d_in, const int* in_sizes, int n_in,
                              void* d_out, int out_size, void* d_ws, size_t ws_size,
                              hipStream_t stream) {
  const float* keys   = (const float*)d_in[0];
  const float* points = (const float*)d_in[1];
  const float* feats  = (const float*)d_in[2];
  const float* nx_w1  = (const float*)d_in[3];
  const float* nx_b1  = (const float*)d_in[4];
  const float* nx_w2  = (const float*)d_in[5];
  const float* nx_b2  = (const float*)d_in[6];
  const float* nx_w3  = (const float*)d_in[7];
  const float* nx_b3  = (const float*)d_in[8];
  // sx_w*/sx_b* (9..14), att_b (16), bn_beta (19): n-constant in softmax -> dead
  const float* att_w  = (const float*)d_in[15];
  const float* att_q  = (const float*)d_in[17];
  const float* gamma  = (const float*)d_in[18];
  float* out = (float*)d_out;

  char* ws = (char*)d_ws;
  unsigned short* idxp = (unsigned short*)(ws + OFF_IDX);
  float* acc  = (float*)(ws + OFF_ACC);
  float* attA = (float*)(ws + OFF_ATTA);
  short* w1f  = (short*)(ws + OFF_W1F);
  short* w2f  = (short*)(ws + OFF_W2F);
  short* w3f  = (short*)(ws + OFF_W3F);

  hipMemsetAsync(acc, 0, 32768, stream);
  topk_kernel<<<2048 + 129, 256, 0, stream>>>(keys, points, feats,
      nx_w1, nx_w2, nx_w3, att_w, att_q, idxp, acc, w1f, w2f, w3f, attA);
  main_kernel<<<512, 512, 0, stream>>>(keys, points, feats, idxp,
      w1f, w2f, w3f, nx_b1, nx_b2, nx_b3, attA, acc, gamma, out);
}

// Round 5
// 160.891 us; speedup vs baseline: 1.2460x; 1.0070x over previous
//
#include <hip/hip_runtime.h>
#include <math.h>

#define BATCH 4
#define KQ    2048
#define NPTS  4096
#define CIN   61
#define KNN   32
#define ROWS  (BATCH*KQ*KNN)   // 262144

// ---------------- ws layout (bytes) ----------------
#define OFF_IDX  0         // u16 [262144] = 524288
#define OFF_ACC  524288    // f32 [64 slots][128] = 32768 (sum 0..63 | sumsq 64..127)
#define OFF_ATTA 557056    // f32[256]
#define OFF_W1F  558080    // bf16 frag-major = 16384
#define OFF_W2F  574464    // 32768
#define OFF_W3F  607232    // 16384 (end 623616)

typedef __attribute__((ext_vector_type(8)))  short bfrag;     // 8 bf16
typedef __attribute__((ext_vector_type(4)))  unsigned ufrag;  // 8 bf16 as 4 u32
typedef __attribute__((ext_vector_type(16))) float cfrag;     // 32x32 acc

__device__ __forceinline__ unsigned short bf16_rne(float x) {
  unsigned u = __float_as_uint(x);
  unsigned r = u + 0x7fffu + ((u >> 16) & 1u);
  return (unsigned short)(r >> 16);
}
__device__ __forceinline__ float4 ld4u(const float* p) {  // 4B-aligned vec load
  float4 r; __builtin_memcpy(&r, p, 16); return r;
}
__device__ __forceinline__ unsigned cvtpk(float lo, float hi) {
  unsigned r;
  asm("v_cvt_pk_bf16_f32 %0, %1, %2" : "=v"(r) : "v"(lo), "v"(hi));
  return r;
}
__device__ __forceinline__ float up_lo(unsigned pk) { return __uint_as_float(pk << 16); }
__device__ __forceinline__ float up_hi(unsigned pk) { return __uint_as_float(pk & 0xffff0000u); }

__device__ __forceinline__ cfrag zero16() {
  cfrag z;
#pragma unroll
  for (int i = 0; i < 16; ++i) z[i] = 0.f;
  return z;
}
__device__ __forceinline__ cfrag mfma_bu(bfrag a, ufrag b, cfrag c) {
  return __builtin_amdgcn_mfma_f32_32x32x16_bf16(a, __builtin_bit_cast(bfrag, b), c, 0, 0, 0);
}
__device__ __forceinline__ cfrag mfma_ub(ufrag a, bfrag b, cfrag c) {
  return __builtin_amdgcn_mfma_f32_32x32x16_bf16(__builtin_bit_cast(bfrag, a), b, c, 0, 0, 0);
}
__device__ __forceinline__ cfrag mfma_uu(ufrag a, ufrag b, cfrag c) {
  return __builtin_amdgcn_mfma_f32_32x32x16_bf16(__builtin_bit_cast(bfrag, a), __builtin_bit_cast(bfrag, b), c, 0, 0, 0);
}

#define NCAND 384   // candidate cap per query (single-wave bound => E ~175)

// exact select of KNN smallest among mcount candidates (NS = ceil(mcount/64)).
template<int NS>
__device__ __forceinline__ void select_emit(
    const unsigned* __restrict__ VAL, const int* __restrict__ IDXL,
    int mcount, unsigned hib, unsigned lob, int lane,
    const float* __restrict__ Pb, float kx, float ky, float kz,
    unsigned short* __restrict__ dst, int* __restrict__ SEL,
    float* __restrict__ accs) {
  const unsigned long long lmask = (1ull << lane) - 1ull;
  unsigned e[NS];
#pragma unroll
  for (int s = 0; s < NS; ++s) {
    int ei = s*64 + lane;
    e[s] = (ei < mcount) ? VAL[ei] : 0xffffffffu;
  }
  unsigned lo2 = lob, hi2 = hib;   // invariant: count(<= hi2) >= KNN
  while (lo2 < hi2) {
    unsigned mid = lo2 + ((hi2 - lo2) >> 1);
    int c = 0;
#pragma unroll
    for (int s = 0; s < NS; ++s) c += (int)__popcll(__ballot(e[s] <= mid));
    if (c == KNN) { hi2 = mid; break; }   // exact set found
    if (c > KNN) hi2 = mid; else lo2 = mid + 1;
  }
  const unsigned T = hi2;
  float r0=0.f,r1=0.f,r2=0.f,r3=0.f,r4=0.f,r5=0.f;
  int base2 = 0;
#pragma unroll
  for (int s = 0; s < NS; ++s) {
    bool p = (e[s] <= T);
    unsigned long long m = __ballot(p);
    if (p) {
      int pos = base2 + (int)__popcll(m & lmask);
      if (pos < KNN) {
        int n = IDXL[s*64 + lane];
        SEL[pos] = n;
        dst[pos] = (unsigned short)n;
        float dx = Pb[n*3+0]-kx, dy = Pb[n*3+1]-ky, dz = Pb[n*3+2]-kz;
        r0 += dx; r1 += dy; r2 += dz;
        r3 += dx*dx; r4 += dy*dy; r5 += dz*dz;
      }
    }
    base2 += (int)__popcll(m);
  }
#pragma unroll
  for (int off = 32; off > 0; off >>= 1) {
    r0 += __shfl_down(r0, off); r1 += __shfl_down(r1, off);
    r2 += __shfl_down(r2, off); r3 += __shfl_down(r3, off);
    r4 += __shfl_down(r4, off); r5 += __shfl_down(r5, off);
  }
  if (lane == 0) {
    atomicAdd(&accs[0], r0); atomicAdd(&accs[1], r1); atomicAdd(&accs[2], r2);
    atomicAdd(&accs[64], r3); atomicAdd(&accs[65], r4); atomicAdd(&accs[66], r5);
  }
}

__device__ __forceinline__ void dispatch_select(
    const unsigned* VAL, const int* IDXL, int mcount, unsigned hib, unsigned lob,
    int lane, const float* Pb, float kx, float ky, float kz,
    unsigned short* dst, int* SEL, float* accs) {
  if (mcount <= 64)
    select_emit<1>(VAL, IDXL, mcount, hib, lob, lane, Pb, kx, ky, kz, dst, SEL, accs);
  else if (mcount <= 128)
    select_emit<2>(VAL, IDXL, mcount, hib, lob, lane, Pb, kx, ky, kz, dst, SEL, accs);
  else if (mcount <= 192)
    select_emit<3>(VAL, IDXL, mcount, hib, lob, lane, Pb, kx, ky, kz, dst, SEL, accs);
  else
    select_emit<6>(VAL, IDXL, mcount, hib, lob, lane, Pb, kx, ky, kz, dst, SEL, accs);
}

// ====== topk: FOUR queries per block, wave w owns query w; prep work is ======
// ====== FOLDED into blocks 0..128 as an epilogue (no tail blocks)      ======
// W2/W3 staged with pi-permuted K so that C-layout -> operand-frag conversion
// in main_kernel is in-lane: k_orig = 32*(kc>>1)+16*(kc&1)+4*h+(j&3)+8*(j>>2).
// W3 staged TRANSPOSED (as B operand: col = out-channel o).
__global__ __launch_bounds__(256, 4) void topk_kernel(
    const float* __restrict__ keys, const float* __restrict__ points,
    const float* __restrict__ feats,
    const float* __restrict__ w1, const float* __restrict__ w2,
    const float* __restrict__ w3,
    const float* __restrict__ att_w, const float* __restrict__ att_q,
    unsigned short* __restrict__ idx_out, float* __restrict__ acc,
    short* __restrict__ w1f, short* __restrict__ w2f, short* __restrict__ w3f,
    float* __restrict__ attA) {
  // ---- topk partition: queries g0..g0+3 (same batch: 2048 % 4 == 0) ----
  __shared__ unsigned VAL[4][NCAND];
  __shared__ int IDXL[4][NCAND];
  __shared__ int SEL[4][KNN];
  __shared__ unsigned HIB[4];
  __shared__ int WTOT[4][4];   // [query][wave]
  __shared__ float FRED[64*33];   // merged 4-query partials, stride-33
  __shared__ float FQ[64*33];
  const int tid = threadIdx.x;
  const int lane = tid & 63, wid = tid >> 6;
  const int g0 = blockIdx.x * 4;
  const int b = g0 >> 11;
  // 4 query keys: block-uniform scalar loads -> SGPRs (frees VGPRs)
  const float kx0 = keys[(size_t)g0*3+0], ky0 = keys[(size_t)g0*3+1],  kz0 = keys[(size_t)g0*3+2];
  const float kx1 = keys[(size_t)g0*3+3], ky1 = keys[(size_t)g0*3+4],  kz1 = keys[(size_t)g0*3+5];
  const float kx2 = keys[(size_t)g0*3+6], ky2 = keys[(size_t)g0*3+7],  kz2 = keys[(size_t)g0*3+8];
  const float kx3 = keys[(size_t)g0*3+9], ky3 = keys[(size_t)g0*3+10], kz3 = keys[(size_t)g0*3+11];
  const float* __restrict__ Pb = points + (size_t)b * NPTS * 3;

  // distances for 4 queries: 16 contiguous points/thread, shared loads
  unsigned u0[16], u1[16], u2[16], u3[16];
  unsigned lm0 = 0xffffffffu, lm1 = 0xffffffffu, lm2 = 0xffffffffu, lm3 = 0xffffffffu;
#pragma unroll
  for (int c4 = 0; c4 < 4; ++c4) {
    const float* pp = Pb + (size_t)(tid*16 + c4*4) * 3;
    float4 A = ld4u(pp), B4 = ld4u(pp + 4), C4 = ld4u(pp + 8);
    float x, y, z, dx, dy, dz;
#define DPT(slot, PX, PY, PZ)                                        \
    x = PX; y = PY; z = PZ;                                          \
    dx = x-kx0; dy = y-ky0; dz = z-kz0;                              \
    u0[slot] = __float_as_uint(dx*dx + dy*dy + dz*dz);               \
    lm0 = min(lm0, u0[slot]);                                        \
    dx = x-kx1; dy = y-ky1; dz = z-kz1;                              \
    u1[slot] = __float_as_uint(dx*dx + dy*dy + dz*dz);               \
    lm1 = min(lm1, u1[slot]);                                        \
    dx = x-kx2; dy = y-ky2; dz = z-kz2;                              \
    u2[slot] = __float_as_uint(dx*dx + dy*dy + dz*dz);               \
    lm2 = min(lm2, u2[slot]);                                        \
    dx = x-kx3; dy = y-ky3; dz = z-kz3;                              \
    u3[slot] = __float_as_uint(dx*dx + dy*dy + dz*dz);               \
    lm3 = min(lm3, u3[slot]);
    DPT(c4*4+0, A.x,  A.y,  A.z)
    DPT(c4*4+1, A.w,  B4.x, B4.y)
    DPT(c4*4+2, B4.z, B4.w, C4.x)
    DPT(c4*4+3, C4.y, C4.z, C4.w)
#undef DPT
  }

  // wave w bounds its OWN query w using its lane-mins (valid global upper
  // bound: each lane-min is a distinct point). Early-exit at count==KNN.
  const unsigned lmw = (wid == 0) ? lm0 : (wid == 1) ? lm1 : (wid == 2) ? lm2 : lm3;
  unsigned wlo = lmw, whi = lmw;
#pragma unroll
  for (int off = 1; off < 64; off <<= 1) {
    unsigned a0 = (unsigned)__shfl_xor((int)wlo, off);
    unsigned a1 = (unsigned)__shfl_xor((int)whi, off);
    wlo = min(wlo, a0); whi = max(whi, a1);
  }
  {
    unsigned lo = wlo, hi = whi;
    while (lo < hi) {
      unsigned mid = lo + ((hi - lo) >> 1);
      int c = (int)__popcll(__ballot(lmw <= mid));
      if (c == KNN) { hi = mid; break; }
      if (c > KNN) hi = mid; else lo = mid + 1;
    }
    if (lane == 0) HIB[wid] = hi;
  }
  __syncthreads();   // S1
  const unsigned hb0 = HIB[0], hb1 = HIB[1], hb2 = HIB[2], hb3 = HIB[3];

  // counts + 4 interleaved exclusive scans
  int c0 = 0, c1 = 0, c2 = 0, c3 = 0;
#pragma unroll
  for (int j = 0; j < 16; ++j) {
    c0 += (u0[j] <= hb0) ? 1 : 0;
    c1 += (u1[j] <= hb1) ? 1 : 0;
    c2 += (u2[j] <= hb2) ? 1 : 0;
    c3 += (u3[j] <= hb3) ? 1 : 0;
  }
  int i0 = c0, i1 = c1, i2 = c2, i3 = c3;
#pragma unroll
  for (int off = 1; off < 64; off <<= 1) {
    int t0 = __shfl_up(i0, off), t1 = __shfl_up(i1, off);
    int t2 = __shfl_up(i2, off), t3 = __shfl_up(i3, off);
    if (lane >= off) { i0 += t0; i1 += t1; i2 += t2; i3 += t3; }
  }
  if (lane == 63) {
    WTOT[0][wid] = i0; WTOT[1][wid] = i1; WTOT[2][wid] = i2; WTOT[3][wid] = i3;
  }
  __syncthreads();   // S2
  int p0 = i0 - c0, p1 = i1 - c1, p2 = i2 - c2, p3 = i3 - c3;
  for (int w = 0; w < wid; ++w) {
    p0 += WTOT[0][w]; p1 += WTOT[1][w]; p2 += WTOT[2][w]; p3 += WTOT[3][w];
  }
#pragma unroll
  for (int j = 0; j < 16; ++j) {
    const int n = tid*16 + j;
    if (u0[j] <= hb0) { if (p0 < NCAND) { VAL[0][p0] = u0[j]; IDXL[0][p0] = n; } ++p0; }
    if (u1[j] <= hb1) { if (p1 < NCAND) { VAL[1][p1] = u1[j]; IDXL[1][p1] = n; } ++p1; }
    if (u2[j] <= hb2) { if (p2 < NCAND) { VAL[2][p2] = u2[j]; IDXL[2][p2] = n; } ++p2; }
    if (u3[j] <= hb3) { if (p3 < NCAND) { VAL[3][p3] = u3[j]; IDXL[3][p3] = n; } ++p3; }
  }
  __syncthreads();   // S3

  // exact select: wave w -> query w (all 4 waves busy)
  float* accs = &acc[(blockIdx.x & 63)*128];
  {
    const int mcount = min(WTOT[wid][0]+WTOT[wid][1]+WTOT[wid][2]+WTOT[wid][3], NCAND);
    const unsigned hibw = (wid == 0) ? hb0 : (wid == 1) ? hb1 : (wid == 2) ? hb2 : hb3;
    const float kxw = (wid == 0) ? kx0 : (wid == 1) ? kx1 : (wid == 2) ? kx2 : kx3;
    const float kyw = (wid == 0) ? ky0 : (wid == 1) ? ky1 : (wid == 2) ? ky2 : ky3;
    const float kzw = (wid == 0) ? kz0 : (wid == 1) ? kz1 : (wid == 2) ? kz2 : kz3;
    dispatch_select(VAL[wid], IDXL[wid], mcount, hibw, wlo, lane, Pb,
                    kxw, kyw, kzw, idx_out + (size_t)(g0 + wid)*KNN, SEL[wid], accs);
  }
  __syncthreads();   // S4: SEL ready

  // feats BN stats merged over 4 queries: rowslot=tid>>3 (32), chunk=tid&7
  {
    const int row = tid >> 3, chunk = tid & 7;
    const int nA = SEL[0][row], nB = SEL[1][row];
    const int nC = SEL[2][row], nD = SEL[3][row];
    const float* frA = feats + ((size_t)b*NPTS + nA)*CIN;
    const float* frB = feats + ((size_t)b*NPTS + nB)*CIN;
    const float* frC = feats + ((size_t)b*NPTS + nC)*CIN;
    const float* frD = feats + ((size_t)b*NPTS + nD)*CIN;
    float fs[8] = {0,0,0,0,0,0,0,0}, fq[8] = {0,0,0,0,0,0,0,0};
    if (chunk < 7) {
      const float* fr[4] = {frA, frB, frC, frD};
#pragma unroll
      for (int qq = 0; qq < 4; ++qq) {
        float4 a0 = ld4u(fr[qq] + chunk*8), a1 = ld4u(fr[qq] + chunk*8 + 4);
        fs[0]+=a0.x; fq[0]+=a0.x*a0.x; fs[1]+=a0.y; fq[1]+=a0.y*a0.y;
        fs[2]+=a0.z; fq[2]+=a0.z*a0.z; fs[3]+=a0.w; fq[3]+=a0.w*a0.w;
        fs[4]+=a1.x; fq[4]+=a1.x*a1.x; fs[5]+=a1.y; fq[5]+=a1.y*a1.y;
        fs[6]+=a1.z; fq[6]+=a1.z*a1.z; fs[7]+=a1.w; fq[7]+=a1.w*a1.w;
      }
    } else {
#pragma unroll
      for (int i = 0; i < 5; ++i) {
        float va = frA[56+i], vb = frB[56+i], vc = frC[56+i], vd = frD[56+i];
        fs[i] = va + vb + vc + vd;
        fq[i] = va*va + vb*vb + vc*vc + vd*vd;
      }
    }
#pragma unroll
    for (int i = 0; i < 8; ++i) {
      FRED[(chunk*8 + i)*33 + row] = fs[i];
      FQ  [(chunk*8 + i)*33 + row] = fq[i];
    }
  }
  __syncthreads();   // S5
  if (tid < 64) {
    float s = 0.f, q2 = 0.f;
#pragma unroll
    for (int r = 0; r < 32; ++r) {
      s  += FRED[tid*33 + r];
      q2 += FQ[tid*33 + r];
    }
    if (tid < CIN) {
      atomicAdd(&accs[3 + tid], s);
      atomicAdd(&accs[64 + 3 + tid], q2);
    }
  }

  // ---- folded prep epilogue: blocks 0..127 convert weights (1 short per
  // thread), block 128 computes attA. No separate tail dispatch. ----
  if (blockIdx.x < 128) {
    const int t = blockIdx.x * 256 + tid;   // 32768 total
    if (t < 8192) {            // W1 (A role): NH=128, K=64 natural, KC=4
      int j = t & 7, ln = (t >> 3) & 63, tk = t >> 9;
      int kc = tk & 3, tile = tk >> 2;
      int nh = tile*32 + (ln & 31), k = kc*16 + (ln >> 5)*8 + j;
      w1f[t] = (short)bf16_rne(w1[k*128 + nh]);
    } else if (t < 24576) {    // W2 (A role): NH=128, K=128 pi-permuted, KC=8
      int t2 = t - 8192;
      int j = t2 & 7, ln = (t2 >> 3) & 63, tk = t2 >> 9;
      int kc = tk & 7, tile = tk >> 3;
      int nh = tile*32 + (ln & 31);
      int k = 32*(kc>>1) + 16*(kc&1) + 4*(ln>>5) + (j&3) + 8*(j>>2);
      w2f[t2] = (short)bf16_rne(w2[k*128 + nh]);
    } else {                   // W3^T (B role): col=o (64), K=128 pi-permuted, KC=8
      int t3 = t - 24576;
      int j = t3 & 7, ln = (t3 >> 3) & 63, tk = t3 >> 9;
      int kc = tk & 7, tile = tk >> 3;
      int nh = tile*32 + (ln & 31);
      int k = 32*(kc>>1) + 16*(kc&1) + 4*(ln>>5) + (j&3) + 8*(j>>2);
      w3f[t3] = (short)bf16_rne(w3[k*64 + nh]);
    }
  } else if (blockIdx.x == 128) {   // attA[c][h] = sum_d att_w[c,h*64+d]*att_q[h,d]
    const int t = tid, c = t >> 2, hh = t & 3;
    float s = 0.f;
    for (int d = 0; d < 64; ++d) s += att_w[c*256 + hh*64 + d] * att_q[hh*64 + d];
    attA[c*4 + hh] = s;
  }
}

// ---------------- main-kernel LDS offsets (bytes) ----------------
#define L_W1F 0        // 16384
#define L_W2F 16384    // 32768
#define L_W3F 49152    // 16384
#define L_SH  65536    // SAe hi frags: 4 kc * 64 * 8 shorts = 4096
#define L_SL  69632    // SAe lo frags: 4096
#define L_B1  73728    // 512
#define L_B2  74240    // 512
#define L_B3  74752    // 256
#define L_WSC 75008    // 8 waves * 512 B w-scratch (phase0: TMP [8][128] f32)
#define L_SC  79104    // f32[64]
#define L_TOT 79360    // < 80 KiB -> 2 blocks/CU

// ====== main: one wave per query, ZERO in-loop barriers ======
// chain: gather(regs) -> E-MFMA(hi/lo) -> in-reg softmax -> w bounce (512B
// per-wave LDS, intra-wave) -> G1 -> G2 -> G3(transposed) -> out-MFMA(hi/lo).
// All C->operand re-frags are in-lane cvt_pk thanks to pi-permuted weights.
// q0's gather is hoisted BEFORE phase0 (hides scatter latency under staging).
__global__ __launch_bounds__(512, 4) void main_kernel(
    const float* __restrict__ keys, const float* __restrict__ points,
    const float* __restrict__ feats, const unsigned short* __restrict__ idxg,
    const short* __restrict__ w1f, const short* __restrict__ w2f,
    const short* __restrict__ w3f,
    const float* __restrict__ b1, const float* __restrict__ b2,
    const float* __restrict__ b3,
    const float* __restrict__ attAg, const float* __restrict__ accg,
    const float* __restrict__ gammav, float* __restrict__ out) {
  __shared__ __align__(16) char smem[L_TOT];
  const int tid = threadIdx.x;
  const int bid = blockIdx.x;
  const int wid = tid >> 6, lane = tid & 63;
  const int col = lane & 31, h = lane >> 5;

  float* WS = (float*)(smem + L_WSC) + wid*128;   // per-wave [32][4]
  const short* SW1 = (const short*)(smem + L_W1F);
  const short* SW2 = (const short*)(smem + L_W2F);
  const short* SW3 = (const short*)(smem + L_W3F);
  const float* SB1 = (const float*)(smem + L_B1);
  const float* SB2 = (const float*)(smem + L_B2);

  // ---- gather + pack (hi + residual lo) for one query ----
  auto gather_pack = [&](int g, int n, ufrag* ahi, ufrag* alo) {
    const int b = g >> 11;
    const float* frow = feats + ((size_t)b*NPTS + n)*CIN;
    float v[4][8];
    if (h == 0) {
      const float* Pb = points + (size_t)b*NPTS*3;
      v[0][0] = Pb[n*3+0] - keys[(size_t)g*3+0];
      v[0][1] = Pb[n*3+1] - keys[(size_t)g*3+1];
      v[0][2] = Pb[n*3+2] - keys[(size_t)g*3+2];
      float4 t0 = ld4u(frow);
      v[0][3]=t0.x; v[0][4]=t0.y; v[0][5]=t0.z; v[0][6]=t0.w;
      v[0][7] = frow[4];
    } else {
      float4 a0 = ld4u(frow+5), a1 = ld4u(frow+9);
      v[0][0]=a0.x; v[0][1]=a0.y; v[0][2]=a0.z; v[0][3]=a0.w;
      v[0][4]=a1.x; v[0][5]=a1.y; v[0][6]=a1.z; v[0][7]=a1.w;
    }
#pragma unroll
    for (int kc = 1; kc < 4; ++kc) {
      const int f0 = kc*16 + 8*h - 3;
      float4 a0 = ld4u(frow+f0), a1 = ld4u(frow+f0+4);
      v[kc][0]=a0.x; v[kc][1]=a0.y; v[kc][2]=a0.z; v[kc][3]=a0.w;
      v[kc][4]=a1.x; v[kc][5]=a1.y; v[kc][6]=a1.z; v[kc][7]=a1.w;
    }
#pragma unroll
    for (int kc = 0; kc < 4; ++kc)
#pragma unroll
      for (int p = 0; p < 4; ++p) {
        unsigned pk = cvtpk(v[kc][2*p], v[kc][2*p+1]);
        ahi[kc][p] = pk;
        alo[kc][p] = cvtpk(v[kc][2*p] - up_lo(pk), v[kc][2*p+1] - up_hi(pk));
      }
  };

  // ---- full per-query chain (E -> softmax -> bounce -> G1 -> G2 -> G3+out) --
  auto chain = [&](int g, const ufrag* ahi, const ufrag* alo) {
    // E: logits [n x hd], hi/lo split (~f32 accurate)
    cfrag Ef = zero16();
#pragma unroll
    for (int kc = 0; kc < 4; ++kc) {
      bfrag sh = *(const bfrag*)((const short*)(smem + L_SH) + (kc*64 + lane)*8);
      bfrag sl = *(const bfrag*)((const short*)(smem + L_SL) + (kc*64 + lane)*8);
      Ef = mfma_ub(ahi[kc], sh, Ef);
      Ef = mfma_ub(alo[kc], sh, Ef);
      Ef = mfma_ub(ahi[kc], sl, Ef);
    }

    // softmax over n (16 regs in-lane + one xor-32)
    float mx = Ef[0];
#pragma unroll
    for (int i = 1; i < 16; ++i) mx = fmaxf(mx, Ef[i]);
    mx = fmaxf(mx, __shfl_xor(mx, 32));
    float wsm[16], ssum = 0.f;
#pragma unroll
    for (int i = 0; i < 16; ++i) { wsm[i] = __expf(Ef[i] - mx); ssum += wsm[i]; }
    ssum += __shfl_xor(ssum, 32);
    const float invs = 1.f / ssum;
#pragma unroll
    for (int i = 0; i < 16; ++i) wsm[i] *= invs;

    // bounce w through per-wave LDS (no barrier: intra-wave)
    if (col < 4) {
#pragma unroll
      for (int i = 0; i < 8; ++i) {
        const int c0 = (2*i & 3) + 8*(i >> 1);   // 0,2,8,10,16,18,24,26
        const int nA = c0 + 4*h;
        WS[nA*4 + col]     = wsm[2*i];
        WS[nA*4 + 4 + col] = wsm[2*i+1];
      }
    }
    const int hdc = col & 3;
    ufrag whi[2], wlo[2];
#pragma unroll
    for (int bb = 0; bb < 2; ++bb)
#pragma unroll
      for (int p = 0; p < 4; ++p) {
        const int c0 = (2*p & 3) + 8*(p >> 1);
        const int n0 = 16*bb + 4*h + c0;
        float r0 = WS[n0*4 + hdc], r1 = WS[n0*4 + 4 + hdc];
        unsigned pk = cvtpk(r0, r1);
        whi[bb][p] = pk;
        wlo[bb][p] = cvtpk(r0 - up_lo(pk), r1 - up_hi(pk));
      }

    // GEMM1: 64 -> 128, relu, in-lane re-frag to A2
    ufrag a2[8];
#pragma unroll
    for (int t = 0; t < 4; ++t) {
      cfrag acc = zero16();
#pragma unroll
      for (int kc = 0; kc < 4; ++kc) {
        bfrag wf = *(const bfrag*)(SW1 + ((t*4 + kc)*64 + lane)*8);
        acc = mfma_bu(wf, ahi[kc], acc);
      }
#pragma unroll
      for (int i = 0; i < 8; ++i) {
        const int c0 = (2*i & 3) + 8*(i >> 1);
        float2 bb2 = *(const float2*)(SB1 + t*32 + c0 + 4*h);
        float x0 = fmaxf(acc[2*i]   + bb2.x, 0.f);
        float x1 = fmaxf(acc[2*i+1] + bb2.y, 0.f);
        a2[2*t + (i>>2)][i&3] = cvtpk(x0, x1);
      }
    }

    // GEMM2: 128 -> 128, relu, re-frag to A3
    ufrag a3[8];
#pragma unroll
    for (int t = 0; t < 4; ++t) {
      cfrag acc = zero16();
#pragma unroll
      for (int kc = 0; kc < 8; ++kc) {
        bfrag wf = *(const bfrag*)(SW2 + ((t*8 + kc)*64 + lane)*8);
        acc = mfma_bu(wf, a2[kc], acc);
      }
#pragma unroll
      for (int i = 0; i < 8; ++i) {
        const int c0 = (2*i & 3) + 8*(i >> 1);
        float2 bb2 = *(const float2*)(SB2 + t*32 + c0 + 4*h);
        float x0 = fmaxf(acc[2*i]   + bb2.x, 0.f);
        float x1 = fmaxf(acc[2*i+1] + bb2.y, 0.f);
        a3[2*t + (i>>2)][i&3] = cvtpk(x0, x1);
      }
    }

    // GEMM3 (transposed: D3'[n][o] = act2^T * W3^T) + out-MFMA
#pragma unroll
    for (int t = 0; t < 2; ++t) {
      cfrag acc = zero16();
#pragma unroll
      for (int kc = 0; kc < 8; ++kc) {
        bfrag wf = *(const bfrag*)(SW3 + ((t*8 + kc)*64 + lane)*8);
        acc = mfma_ub(a3[kc], wf, acc);
      }
      const float bz = ((const float*)(smem + L_B3))[t*32 + col];
#pragma unroll
      for (int i = 0; i < 16; ++i) acc[i] += bz;
      // lat^T re-frag (hi + lo)
      ufrag lh[2], ll[2];
#pragma unroll
      for (int i = 0; i < 8; ++i) {
        unsigned pk = cvtpk(acc[2*i], acc[2*i+1]);
        lh[i>>2][i&3] = pk;
        ll[i>>2][i&3] = cvtpk(acc[2*i] - up_lo(pk), acc[2*i+1] - up_hi(pk));
      }
      cfrag og = zero16();
#pragma unroll
      for (int bb = 0; bb < 2; ++bb) og = mfma_uu(lh[bb], whi[bb], og);
#pragma unroll
      for (int bb = 0; bb < 2; ++bb) og = mfma_uu(ll[bb], whi[bb], og);
#pragma unroll
      for (int bb = 0; bb < 2; ++bb) og = mfma_uu(lh[bb], wlo[bb], og);
      if (col < 4) {
        float* op = out + (size_t)g*256 + t*128 + col;
#pragma unroll
        for (int i = 0; i < 16; ++i) {
          const int orow = (i&3) + 8*(i>>2) + 4*h;
          op[orow*4] = og[i];
        }
      }
    }
  };

  // ---- hoisted q0 gather (+ q1 idx prefetch): hides under phase0 staging ----
  const int g0q = bid*8 + wid;
  const int g1q = g0q + 4096;
  const int n0 = (int)idxg[(size_t)g0q*KNN + col];
  const int n1 = (int)idxg[(size_t)g1q*KNN + col];
  ufrag ahi0[4], alo0[4];
  gather_pack(g0q, n0, ahi0, alo0);

  // ---- phase 0: stage weights + compute Ae = gamma*invstd*attA ----
  {
    // weight frags: w1f|w2f|w3f contiguous in ws = 65536 B = 4096 uint4
    const uint4* src = (const uint4*)w1f;
    uint4* dst = (uint4*)smem;
#pragma unroll
    for (int r = 0; r < 8; ++r) dst[r*512 + tid] = src[r*512 + tid];
    if (tid < 128) ((float*)(smem + L_B1))[tid] = b1[tid];
    else if (tid < 256) ((float*)(smem + L_B2))[tid-128] = b2[tid-128];
    else if (tid < 320) ((float*)(smem + L_B3))[tid-256] = b3[tid-256];
    // BN stats reduce
    float* TMP = (float*)(smem + L_WSC);    // [8][128]
    {
      int c = tid & 63, p = tid >> 6;
      float s = 0.f, s2 = 0.f;
      for (int k = p; k < 64; k += 8) {
        s += accg[k*128 + c]; s2 += accg[k*128 + 64 + c];
      }
      TMP[p*128 + c] = s; TMP[p*128 + 64 + c] = s2;
    }
    __syncthreads();
    float* SCp = (float*)(smem + L_SC);
    if (tid < 64) {
      float s = 0.f, s2 = 0.f;
#pragma unroll
      for (int p = 0; p < 8; ++p) { s += TMP[p*128 + tid]; s2 += TMP[p*128 + 64 + tid]; }
      const float invR = 1.f / (float)ROWS;
      float mean = s * invR;
      float var = s2 * invR - mean * mean;
      SCp[tid] = gammav[tid] * rsqrtf(var + 1e-5f);
    }
    __syncthreads();
    // SAe hi/lo frags (B role: col=hd (<4 valid), k natural pi1)
    {
      const int s = tid >> 8;           // 0 = hi, 1 = lo
      const int kc = (tid >> 6) & 3;
      const int ln = tid & 63;
      const int hd = ln & 31;
      short* dstf = (short*)(smem + (s ? L_SL : L_SH)) + (kc*64 + ln)*8;
#pragma unroll
      for (int j = 0; j < 8; ++j) {
        const int ch = kc*16 + (ln>>5)*8 + j;
        float val = (hd < 4) ? attAg[ch*4 + hd] * SCp[ch] : 0.f;
        unsigned hb = bf16_rne(val);
        if (s) {
          float lo = val - __uint_as_float(hb << 16);
          dstf[j] = (short)bf16_rne(lo);
        } else {
          dstf[j] = (short)hb;
        }
      }
    }
    __syncthreads();
  }

  // ---- q0 (gather already in registers) ----
  chain(g0q, ahi0, alo0);

  // ---- q1 (idx prefetched; gather now) ----
  ufrag ahi1[4], alo1[4];
  gather_pack(g1q, n1, ahi1, alo1);
  chain(g1q, ahi1, alo1);
}

extern "C" void kernel_launch(void* const* d_in, const int* in_sizes, int n_in,
                              void* d_out, int out_size, void* d_ws, size_t ws_size,
                              hipStream_t stream) {
  const float* keys   = (const float*)d_in[0];
  const float* points = (const float*)d_in[1];
  const float* feats  = (const float*)d_in[2];
  const float* nx_w1  = (const float*)d_in[3];
  const float* nx_b1  = (const float*)d_in[4];
  const float* nx_w2  = (const float*)d_in[5];
  const float* nx_b2  = (const float*)d_in[6];
  const float* nx_w3  = (const float*)d_in[7];
  const float* nx_b3  = (const float*)d_in[8];
  // sx_w*/sx_b* (9..14), att_b (16), bn_beta (19): n-constant in softmax -> dead
  const float* att_w  = (const float*)d_in[15];
  const float* att_q  = (const float*)d_in[17];
  const float* gamma  = (const float*)d_in[18];
  float* out = (float*)d_out;

  char* ws = (char*)d_ws;
  unsigned short* idxp = (unsigned short*)(ws + OFF_IDX);
  float* acc  = (float*)(ws + OFF_ACC);
  float* attA = (float*)(ws + OFF_ATTA);
  short* w1f  = (short*)(ws + OFF_W1F);
  short* w2f  = (short*)(ws + OFF_W2F);
  short* w3f  = (short*)(ws + OFF_W3F);

  hipMemsetAsync(acc, 0, 32768, stream);
  topk_kernel<<<2048, 256, 0, stream>>>(keys, points, feats,
      nx_w1, nx_w2, nx_w3, att_w, att_q, idxp, acc, w1f, w2f, w3f, attA);
  main_kernel<<<512, 512, 0, stream>>>(keys, points, feats, idxp,
      w1f, w2f, w3f, nx_b1, nx_b2, nx_b3, attA, acc, gamma, out);
}